// Round 8
// baseline (274.043 us; speedup 1.0000x reference)
//
#include <hip/hip_runtime.h>

// TriAttention factorized implementation — all-f32 I/O, bf16 MFMA logits.
// dims: B=16, N(v,q,a)=96, D=256, H=128, G=2
// l[v,q,a,g] = sum_h (qt[q,h]*Wg[h,g]) * (at[a,h]*vt[v,h]); contractions
// factor through pairwise marginals of softmax(l) (p never materialized).
// R8 k_logits: barrier-free v-loop. at staged RAW once (26 KB LDS);
// A frags (qt*Wg) register-cached per wave; B frags scaled on ds_read by
// vt[v]. grid 768 (CV=4) -> 3 WG/CU. E_qa partials stored bf16 (NCH=24);
// k_reduce parallelized to grid 1152.

#define B_  16
#define N_  96
#define D_  256
#define H_  128
#define CV  4     // v rows per k_logits workgroup
#define NCH 24    // v-chunks = 96/CV
#define PAD 136   // LDS row stride in bf16 elems (272 B, 16B-aligned)

typedef short bf16x8_t __attribute__((ext_vector_type(8)));
typedef float f32x4_t  __attribute__((ext_vector_type(4)));

__device__ __forceinline__ float bf2f(unsigned short u) {
    union { unsigned u32; float f; } x;
    x.u32 = ((unsigned)u) << 16;
    return x.f;
}
__device__ __forceinline__ unsigned short f2bf(float f) {
    union { float f; unsigned u; } x;
    x.f = f;
    unsigned r = x.u + 0x7fffu + ((x.u >> 16) & 1u);   // RNE
    return (unsigned short)(r >> 16);
}

// ---------------------------------------------------------------------------
// Kernel 1: six projections x@W+b -> [B,96,128]; tucker (p<3) relu'd + bf16,
// value projections (p>=3) f32. grid = 768 (3 WG/CU), 12 tokens/WG.
// ---------------------------------------------------------------------------
__global__ __launch_bounds__(256) void k_proj(
    const float* __restrict__ v, const float* __restrict__ q,
    const float* __restrict__ a,
    const float* __restrict__ Wvt, const float* __restrict__ bvt,
    const float* __restrict__ Wqt, const float* __restrict__ bqt,
    const float* __restrict__ Wat, const float* __restrict__ bat,
    const float* __restrict__ Wvp, const float* __restrict__ bvp,
    const float* __restrict__ Wqp, const float* __restrict__ bqp,
    const float* __restrict__ Wap, const float* __restrict__ bap,
    unsigned short* __restrict__ vt_o, unsigned short* __restrict__ qt_o,
    unsigned short* __restrict__ at_o,
    float* __restrict__ vp_o, float* __restrict__ qp_o, float* __restrict__ ap_o)
{
    int wg = blockIdx.x;
    int tc = wg % 8, b = (wg / 8) & 15, p = wg / 128;
    const float* xs_[6] = {v, q, a, v, q, a};
    const float* Ws_[6] = {Wvt, Wqt, Wat, Wvp, Wqp, Wap};
    const float* bs_[6] = {bvt, bqt, bat, bvp, bqp, bap};

    __shared__ __align__(16) float x_l[12 * D_];   // 12 KB

    int tid = threadIdx.x;
    int t0 = tc * 12;
    const float* x = xs_[p] + (size_t)(b * N_ + t0) * D_;
    for (int i = tid; i < 768; i += 256)
        ((float4*)x_l)[i] = ((const float4*)x)[i];
    __syncthreads();

    int d = tid & 127, tg = tid >> 7;
    const float* W = Ws_[p];
    float bias = bs_[p][d];
    float acc[6];
#pragma unroll
    for (int t = 0; t < 6; t++) acc[t] = bias;

    for (int kb = 0; kb < 32; kb++) {
        int k = kb * 8;
        float w0 = W[(k + 0) * H_ + d], w1 = W[(k + 1) * H_ + d];
        float w2 = W[(k + 2) * H_ + d], w3 = W[(k + 3) * H_ + d];
        float w4 = W[(k + 4) * H_ + d], w5 = W[(k + 5) * H_ + d];
        float w6 = W[(k + 6) * H_ + d], w7 = W[(k + 7) * H_ + d];
#pragma unroll
        for (int t = 0; t < 6; t++) {
            int lt = tg * 6 + t;
            float4 xa = *(const float4*)&x_l[lt * D_ + k];
            float4 xb = *(const float4*)&x_l[lt * D_ + k + 4];
            acc[t] += xa.x * w0 + xa.y * w1 + xa.z * w2 + xa.w * w3
                    + xb.x * w4 + xb.y * w5 + xb.z * w6 + xb.w * w7;
        }
    }

    int trow = b * N_ + t0 + tg * 6;
    if (p < 3) {
        unsigned short* outs[3] = {vt_o, qt_o, at_o};
        unsigned short* o = outs[p];
#pragma unroll
        for (int t = 0; t < 6; t++)
            o[(trow + t) * H_ + d] = f2bf(fmaxf(acc[t], 0.f));   // FCNet relu
    } else {
        float* outs[3] = {vp_o, qp_o, ap_o};
        float* o = outs[p - 3];
#pragma unroll
        for (int t = 0; t < 6; t++) o[(trow + t) * H_ + d] = acc[t];
    }
}

// ---------------------------------------------------------------------------
// Kernel 2 (R8): logits + exp + marginals. WG = (b, vc of CV=4, g), grid 768.
// Barrier-free v-loop: at staged RAW in LDS once; A frags = qt*Wg register-
// cached per wave (12 bf16x8); B frags = ds_read(at) * vt8[v] on the fly.
// E_vq/E_va accumulate in per-vl LDS arrays via LDS atomics (no mid-loop
// barriers); single barrier before coalesced writeback. E_qa partials ->
// bf16 coalesced stores (reduced by k_reduce).
// ---------------------------------------------------------------------------
__global__ __launch_bounds__(256, 3) void k_logits(
    const unsigned short* __restrict__ vt, const unsigned short* __restrict__ qt,
    const unsigned short* __restrict__ at, const float* __restrict__ Wg,
    float* __restrict__ E_vq, float* __restrict__ E_va,
    unsigned short* __restrict__ E_qa_part)
{
    int bid = blockIdx.x;
    int g = bid & 1, vc = (bid >> 1) % NCH, b = bid / (2 * NCH);
    int tid = threadIdx.x;

    __shared__ __align__(16) unsigned short at_l[N_ * PAD];  // 26112 B, raw at
    __shared__ float evq_l[CV][N_];
    __shared__ float eva_l[CV][N_];

    const unsigned short* qtb = qt + (size_t)b * N_ * H_;
    const unsigned short* atb = at + (size_t)b * N_ * H_;

    // zero per-vl accumulators (before the single barrier)
    if (tid < 96) {
#pragma unroll
        for (int vl = 0; vl < CV; vl++) evq_l[vl][tid] = 0.f;
    } else if (tid < 192) {
#pragma unroll
        for (int vl = 0; vl < CV; vl++) eva_l[vl][tid - 96] = 0.f;
    }
    // stage raw at (no conversion, straight copy)
    for (int it = 0; it < 12; it++) {
        int i = tid + it * 256;
        int e = i * 4, t = e >> 7, h = e & 127;
        *(ushort4*)&at_l[t * PAD + h] = *(const ushort4*)&atb[e];
    }

    int wave = tid >> 6, lane = tid & 63, quad = lane >> 4, l15 = lane & 15;
    int qi0 = (wave >> 1) * 3, aj0 = (wave & 1) * 3;

    // A fragments: load qt from global (L2-hot, coalesced 64B rows), scale by
    // Wg[:,g], keep in registers for the whole kernel (12 x bf16x8 = 48 VGPR).
    bf16x8_t afr[3][4];
    {
        float wgf[4][8];
#pragma unroll
        for (int ks = 0; ks < 4; ks++)
#pragma unroll
            for (int j = 0; j < 8; j++)
                wgf[ks][j] = Wg[(ks * 32 + quad * 8 + j) * 2 + g];
#pragma unroll
        for (int i = 0; i < 3; i++)
#pragma unroll
            for (int ks = 0; ks < 4; ks++) {
                bf16x8_t raw = *(const bf16x8_t*)&qtb[((qi0 + i) * 16 + l15) * H_ + ks * 32 + quad * 8];
                bf16x8_t o;
#pragma unroll
                for (int j = 0; j < 8; j++)
                    o[j] = (short)f2bf(bf2f((unsigned short)raw[j]) * wgf[ks][j]);
                afr[i][ks] = o;
            }
    }
    __syncthreads();   // at_l + evq/eva zero ready

    float eqa[3][3][4];
#pragma unroll
    for (int i = 0; i < 3; i++)
#pragma unroll
        for (int j = 0; j < 3; j++)
#pragma unroll
            for (int r = 0; r < 4; r++) eqa[i][j][r] = 0.f;

    for (int vl = 0; vl < CV; vl++) {
        int vrow = vc * CV + vl;
        const unsigned short* vrp = vt + ((size_t)b * N_ + vrow) * H_;
        bf16x8_t vt8[4];
#pragma unroll
        for (int ks = 0; ks < 4; ks++)
            vt8[ks] = *(const bf16x8_t*)&vrp[ks * 32 + quad * 8];

        f32x4_t acc[3][3];
#pragma unroll
        for (int i = 0; i < 3; i++)
#pragma unroll
            for (int j = 0; j < 3; j++)
                acc[i][j] = (f32x4_t){0.f, 0.f, 0.f, 0.f};

#pragma unroll
        for (int ks = 0; ks < 4; ks++) {
            float vtf[8];
#pragma unroll
            for (int j = 0; j < 8; j++) vtf[j] = bf2f((unsigned short)vt8[ks][j]);
            bf16x8_t bfr[3];
#pragma unroll
            for (int jt = 0; jt < 3; jt++) {
                bf16x8_t raw = *(const bf16x8_t*)&at_l[((aj0 + jt) * 16 + l15) * PAD + ks * 32 + quad * 8];
                bf16x8_t o;
#pragma unroll
                for (int j = 0; j < 8; j++)
                    o[j] = (short)f2bf(bf2f((unsigned short)raw[j]) * vtf[j]);
                bfr[jt] = o;
            }
#pragma unroll
            for (int i = 0; i < 3; i++)
#pragma unroll
                for (int jt = 0; jt < 3; jt++)
                    acc[i][jt] = __builtin_amdgcn_mfma_f32_16x16x32_bf16(afr[i][ks], bfr[jt], acc[i][jt], 0, 0, 0);
        }

        // C/D: col(a)=l15, row(q)=quad*4+r  [m89-verified]
        float s[3][4];
        float c[3];
#pragma unroll
        for (int i = 0; i < 3; i++) {
            s[i][0] = 0.f; s[i][1] = 0.f; s[i][2] = 0.f; s[i][3] = 0.f;
        }
        c[0] = 0.f; c[1] = 0.f; c[2] = 0.f;
#pragma unroll
        for (int i = 0; i < 3; i++)
#pragma unroll
            for (int jt = 0; jt < 3; jt++) {
                float e0 = __expf(fminf(fmaxf(acc[i][jt][0], -30.f), 30.f));
                float e1 = __expf(fminf(fmaxf(acc[i][jt][1], -30.f), 30.f));
                float e2 = __expf(fminf(fmaxf(acc[i][jt][2], -30.f), 30.f));
                float e3 = __expf(fminf(fmaxf(acc[i][jt][3], -30.f), 30.f));
                eqa[i][jt][0] += e0; eqa[i][jt][1] += e1;
                eqa[i][jt][2] += e2; eqa[i][jt][3] += e3;
                s[i][0] += e0; s[i][1] += e1; s[i][2] += e2; s[i][3] += e3;
                c[jt] += e0 + e1 + e2 + e3;
            }
        // E_vq rows: reduce over l15; LDS atomics combine the 2 aj-waves.
#pragma unroll
        for (int i = 0; i < 3; i++) {
            float s0 = s[i][0], s1 = s[i][1], s2 = s[i][2], s3 = s[i][3];
#pragma unroll
            for (int m = 1; m < 16; m <<= 1) {
                s0 += __shfl_xor(s0, m); s1 += __shfl_xor(s1, m);
                s2 += __shfl_xor(s2, m); s3 += __shfl_xor(s3, m);
            }
            if (l15 == 0) {
                int qr = (qi0 + i) * 16 + quad * 4;
                atomicAdd(&evq_l[vl][qr + 0], s0);
                atomicAdd(&evq_l[vl][qr + 1], s1);
                atomicAdd(&evq_l[vl][qr + 2], s2);
                atomicAdd(&evq_l[vl][qr + 3], s3);
            }
        }
        // E_va cols: reduce over quads; LDS atomics combine the 2 qi-waves.
#pragma unroll
        for (int jt = 0; jt < 3; jt++) {
            float cs = c[jt];
            cs += __shfl_xor(cs, 16);
            cs += __shfl_xor(cs, 32);
            if (lane < 16) atomicAdd(&eva_l[vl][(aj0 + jt) * 16 + l15], cs);
        }
        // no barrier: accumulation is commutative; sync only before writeback
    }
    __syncthreads();

    // coalesced writeback of all CV rows
#pragma unroll
    for (int vl = 0; vl < CV; vl++) {
        int base = ((b * 2 + g) * N_ + vc * CV + vl) * N_;
        if (tid < 96) E_vq[base + tid] = evq_l[vl][tid];
        else if (tid < 192) E_va[base + tid - 96] = eva_l[vl][tid - 96];
    }

    // E_qa partial flush: bf16 coalesced stores, layout [slot][idx][tid]
    unsigned short* Pp = E_qa_part + (size_t)((b * NCH + vc) * 2 + g) * 9216;
#pragma unroll
    for (int i = 0; i < 3; i++)
#pragma unroll
        for (int jt = 0; jt < 3; jt++)
#pragma unroll
            for (int r = 0; r < 4; r++) {
                int idx = (i * 3 + jt) * 4 + r;
                Pp[idx * 256 + tid] = f2bf(eqa[i][jt][r]);
            }
}

// ---------------------------------------------------------------------------
// Kernel 3 (R8): reduce bf16 E_qa partials over NCH vc slots. grid = 1152
// ((b,g) x 36 idx); coalesced 512B bursts per load.
// ---------------------------------------------------------------------------
__global__ __launch_bounds__(256) void k_reduce(
    const unsigned short* __restrict__ E_qa_part, float* __restrict__ E_qa)
{
    int wg = blockIdx.x;
    int idx = wg % 36, bg = wg / 36;
    int b = bg >> 1, g = bg & 1;
    int tid = threadIdx.x;

    float s = 0.f;
    const unsigned short* Pp = E_qa_part + (size_t)(b * NCH * 2 + g) * 9216 + idx * 256 + tid;
#pragma unroll
    for (int vc = 0; vc < NCH; vc++) s += bf2f(Pp[(size_t)vc * 2 * 9216]);

    int wave = tid >> 6, lane = tid & 63, quad = lane >> 4, l15 = lane & 15;
    int qi0 = (wave >> 1) * 3, aj0 = (wave & 1) * 3;
    int i = idx / 12, jt = (idx / 4) % 3, r = idx & 3;
    int qq = (qi0 + i) * 16 + quad * 4 + r;
    int aa = (aj0 + jt) * 16 + l15;
    E_qa[(size_t)bg * 9216 + qq * 96 + aa] = s;
}

// ---------------------------------------------------------------------------
// Kernel 4: Z = sum(E_vq) per (b,g); Zinv = 1/Z. grid = 32.
// ---------------------------------------------------------------------------
__global__ __launch_bounds__(256) void k_zsum(
    const float* __restrict__ E_vq, float* __restrict__ Zinv)
{
    int b = blockIdx.x >> 1, g = blockIdx.x & 1;
    int tid = threadIdx.x;
    float z = 0.f;
    const float* ev = E_vq + (b * 2 + g) * 9216;
    for (int i = tid; i < 9216; i += 256) z += ev[i];
    __shared__ float red[256];
    red[tid] = z;
    __syncthreads();
    for (int s = 128; s > 0; s >>= 1) {
        if (tid < s) red[tid] += red[tid + s];
        __syncthreads();
    }
    if (tid == 0) Zinv[b * 2 + g] = 1.f / fmaxf(red[0], 1e-30f);
}

// ---------------------------------------------------------------------------
// Kernel 5: attended contexts from marginals; c written f32 directly into
// d_out at final positions (c_v/c_q col=g*128+d, c_a col=d*2+g). grid = 576.
// ---------------------------------------------------------------------------
__global__ __launch_bounds__(256) void k_ctx(
    const float* __restrict__ E_vq, const float* __restrict__ E_va,
    const float* __restrict__ E_qa,
    const float* __restrict__ vp, const float* __restrict__ qp,
    const float* __restrict__ ap, const float* __restrict__ Zinv,
    float* __restrict__ out)
{
    int wg = blockIdx.x;
    int tc = wg % 6, g = (wg / 6) & 1, b = (wg / 12) & 15, o = wg / 192;
    int tid = threadIdx.x;
    __shared__ __align__(16) float E1l[16 * 100];
    __shared__ __align__(16) float E2l[16 * 100];
    int t0 = tc * 16;
    const float* Evq = E_vq + (b * 2 + g) * 9216;
    const float* Eva = E_va + (b * 2 + g) * 9216;
    const float* Eqa = E_qa + (b * 2 + g) * 9216;

    if (o == 0) {
        for (int i = tid; i < 1536; i += 256) {
            int t = i / 96, j = i - t * 96;
            E1l[t * 100 + j] = Evq[(t0 + t) * 96 + j];
            E2l[t * 100 + j] = Eva[(t0 + t) * 96 + j];
        }
    } else if (o == 1) {
        for (int i = tid; i < 1536; i += 256) {
            int t = i & 15, j = i >> 4;
            E1l[t * 100 + j] = Evq[j * 96 + t0 + t];
        }
        for (int i = tid; i < 1536; i += 256) {
            int t = i / 96, j = i - t * 96;
            E2l[t * 100 + j] = Eqa[(t0 + t) * 96 + j];
        }
    } else {
        for (int i = tid; i < 1536; i += 256) {
            int t = i & 15, j = i >> 4;
            E1l[t * 100 + j] = Eva[j * 96 + t0 + t];
            E2l[t * 100 + j] = Eqa[j * 96 + t0 + t];
        }
    }
    __syncthreads();

    const float* P1 = ((o == 0) ? qp : vp) + b * N_ * H_;
    const float* P2 = ((o == 2) ? qp : ap) + b * N_ * H_;
    int d = tid & 127, tg = tid >> 7;
    float acc[8] = {0.f, 0.f, 0.f, 0.f, 0.f, 0.f, 0.f, 0.f};
    for (int jb = 0; jb < 24; jb++) {
        int j4 = jb * 4;
        float p10 = P1[(j4 + 0) * H_ + d], p11 = P1[(j4 + 1) * H_ + d];
        float p12 = P1[(j4 + 2) * H_ + d], p13 = P1[(j4 + 3) * H_ + d];
        float p20 = P2[(j4 + 0) * H_ + d], p21 = P2[(j4 + 1) * H_ + d];
        float p22 = P2[(j4 + 2) * H_ + d], p23 = P2[(j4 + 3) * H_ + d];
#pragma unroll
        for (int t8 = 0; t8 < 8; t8++) {
            int t = tg * 8 + t8;
            float4 e1 = *(const float4*)&E1l[t * 100 + j4];
            float4 e2 = *(const float4*)&E2l[t * 100 + j4];
            acc[t8] += e1.x * p10 + e1.y * p11 + e1.z * p12 + e1.w * p13
                     + e2.x * p20 + e2.y * p21 + e2.z * p22 + e2.w * p23;
        }
    }
    float zi = Zinv[b * 2 + g];
    float* ob = out + (size_t)((o * B_ + b) * N_) * 256;
#pragma unroll
    for (int t8 = 0; t8 < 8; t8++) {
        int T = t0 + tg * 8 + t8;
        int col = (o == 2) ? (d * 2 + g) : (g * 128 + d);
        ob[T * 256 + col] = acc[t8] * zi;
    }
}

// ---------------------------------------------------------------------------
// Kernel 6: updated_x = x + c_x @ Wxu + bxu, in place over d_out. grid = 576.
// ---------------------------------------------------------------------------
__global__ __launch_bounds__(256) void k_update(
    const float* __restrict__ v, const float* __restrict__ q,
    const float* __restrict__ a,
    const float* __restrict__ Wvu, const float* __restrict__ bvu,
    const float* __restrict__ Wqu, const float* __restrict__ bqu,
    const float* __restrict__ Wau, const float* __restrict__ bau,
    float* __restrict__ out)
{
    int wg = blockIdx.x;
    int tc = wg % 12, b = (wg / 12) & 15, o = wg / 192;
    int tid = threadIdx.x;
    const float* xs_[3] = {v, q, a};
    const float* Ws_[3] = {Wvu, Wqu, Wau};
    const float* bs_[3] = {bvu, bqu, bau};
    int t0 = tc * 8;

    __shared__ __align__(16) float c_l[8 * 256];
    float* cbase = out + (size_t)((o * B_ + b) * N_ + t0) * 256;
    for (int i = tid; i < 2048; i += 256) c_l[i] = cbase[i];
    __syncthreads();

    const float* W = Ws_[o];
    const float* x = xs_[o] + (size_t)(b * N_ + t0) * 256;
    float bias = bs_[o][tid];
    float acc[8];
#pragma unroll
    for (int t = 0; t < 8; t++) acc[t] = bias + x[t * 256 + tid];

    for (int kb = 0; kb < 64; kb++) {
        int k = kb * 4;
        float w0 = W[(k + 0) * 256 + tid];
        float w1 = W[(k + 1) * 256 + tid];
        float w2 = W[(k + 2) * 256 + tid];
        float w3 = W[(k + 3) * 256 + tid];
#pragma unroll
        for (int t = 0; t < 8; t++) {
            float4 c4 = *(const float4*)&c_l[t * 256 + k];
            acc[t] += c4.x * w0 + c4.y * w1 + c4.z * w2 + c4.w * w3;
        }
    }
#pragma unroll
    for (int t = 0; t < 8; t++) cbase[t * 256 + tid] = acc[t];
}

// ---------------------------------------------------------------------------
extern "C" void kernel_launch(void* const* d_in, const int* in_sizes, int n_in,
                              void* d_out, int out_size, void* d_ws, size_t ws_size,
                              hipStream_t stream)
{
    const float* v   = (const float*)d_in[0];
    const float* q   = (const float*)d_in[1];
    const float* a   = (const float*)d_in[2];
    const float* Wvt = (const float*)d_in[3];
    const float* bvt = (const float*)d_in[4];
    const float* Wqt = (const float*)d_in[5];
    const float* bqt = (const float*)d_in[6];
    const float* Wat = (const float*)d_in[7];
    const float* bat = (const float*)d_in[8];
    const float* Wg  = (const float*)d_in[9];
    const float* Wvp = (const float*)d_in[10];
    const float* bvp = (const float*)d_in[11];
    const float* Wqp = (const float*)d_in[12];
    const float* bqp = (const float*)d_in[13];
    const float* Wap = (const float*)d_in[14];
    const float* bap = (const float*)d_in[15];
    const float* Wvu = (const float*)d_in[16];
    const float* bvu = (const float*)d_in[17];
    const float* Wqu = (const float*)d_in[18];
    const float* bqu = (const float*)d_in[19];
    const float* Wau = (const float*)d_in[20];
    const float* bau = (const float*)d_in[21];

    char* ws = (char*)d_ws;
    size_t off = 0;
    auto alloc = [&](size_t bytes) {
        char* p = ws + off;
        off += (bytes + 255) & ~(size_t)255;
        return (void*)p;
    };
    unsigned short* vt = (unsigned short*)alloc((size_t)B_ * N_ * H_ * 2);
    unsigned short* qt = (unsigned short*)alloc((size_t)B_ * N_ * H_ * 2);
    unsigned short* at = (unsigned short*)alloc((size_t)B_ * N_ * H_ * 2);
    float* vpb  = (float*)alloc((size_t)B_ * N_ * H_ * 4);
    float* qpb  = (float*)alloc((size_t)B_ * N_ * H_ * 4);
    float* apb  = (float*)alloc((size_t)B_ * N_ * H_ * 4);
    float* E_vq = (float*)alloc((size_t)B_ * 2 * 9216 * 4);
    float* E_va = (float*)alloc((size_t)B_ * 2 * 9216 * 4);
    float* E_qa = (float*)alloc((size_t)B_ * 2 * 9216 * 4);
    float* Zinv = (float*)alloc(256);
    unsigned short* E_qa_part =
        (unsigned short*)alloc((size_t)B_ * NCH * 2 * 9216 * 2);  // 14.2 MB bf16
    // total ~21 MB

    k_proj<<<768, 256, 0, stream>>>(v, q, a, Wvt, bvt, Wqt, bqt, Wat, bat,
                                    Wvp, bvp, Wqp, bqp, Wap, bap,
                                    vt, qt, at, vpb, qpb, apb);
    k_logits<<<B_ * NCH * 2, 256, 0, stream>>>(vt, qt, at, Wg,
                                               E_vq, E_va, E_qa_part);
    k_reduce<<<1152, 256, 0, stream>>>(E_qa_part, E_qa);
    k_zsum<<<32, 256, 0, stream>>>(E_vq, Zinv);
    k_ctx<<<576, 256, 0, stream>>>(E_vq, E_va, E_qa, vpb, qpb, apb, Zinv,
                                   (float*)d_out);
    k_update<<<576, 256, 0, stream>>>(v, q, a, Wvu, bvu, Wqu, bqu, Wau, bau,
                                      (float*)d_out);
}

// Round 9
// 225.104 us; speedup vs baseline: 1.2174x; 1.2174x over previous
//
#include <hip/hip_runtime.h>

// TriAttention factorized implementation — all-f32 I/O, bf16 MFMA logits.
// dims: B=16, N(v,q,a)=96, D=256, H=128, G=2
// l[v,q,a,g] = sum_h (qt[q,h]*Wg[h,g]) * (at[a,h]*vt[v,h]); contractions
// factor through pairwise marginals of softmax(l) (p never materialized).
// R9 k_logits: barrier-free v-loop with BOTH operands in LDS (qg scaled
// once, at raw; B scaled on ds_read by vt[v]); marginal halves written to
// global partials (no LDS atomics/barriers), merged in k_merge.
// NO __launch_bounds__ min-waves cap (R8's cap caused VGPR spill -> 236 MB
// scratch traffic). LDS 52.2 KB -> 3 WG/CU; grid 768.

#define B_  16
#define N_  96
#define D_  256
#define H_  128
#define CV  4     // v rows per k_logits workgroup
#define NCH 24    // v-chunks = 96/CV
#define PAD 136   // LDS row stride in bf16 elems (272 B, 16B-aligned)

typedef short bf16x8_t __attribute__((ext_vector_type(8)));
typedef float f32x4_t  __attribute__((ext_vector_type(4)));

__device__ __forceinline__ float bf2f(unsigned short u) {
    union { unsigned u32; float f; } x;
    x.u32 = ((unsigned)u) << 16;
    return x.f;
}
__device__ __forceinline__ unsigned short f2bf(float f) {
    union { float f; unsigned u; } x;
    x.f = f;
    unsigned r = x.u + 0x7fffu + ((x.u >> 16) & 1u);   // RNE
    return (unsigned short)(r >> 16);
}

// ---------------------------------------------------------------------------
// Kernel 1: six projections x@W+b -> [B,96,128]; tucker (p<3) relu'd + bf16,
// value projections (p>=3) f32. grid = 768 (3 WG/CU), 12 tokens/WG.
// ---------------------------------------------------------------------------
__global__ __launch_bounds__(256) void k_proj(
    const float* __restrict__ v, const float* __restrict__ q,
    const float* __restrict__ a,
    const float* __restrict__ Wvt, const float* __restrict__ bvt,
    const float* __restrict__ Wqt, const float* __restrict__ bqt,
    const float* __restrict__ Wat, const float* __restrict__ bat,
    const float* __restrict__ Wvp, const float* __restrict__ bvp,
    const float* __restrict__ Wqp, const float* __restrict__ bqp,
    const float* __restrict__ Wap, const float* __restrict__ bap,
    unsigned short* __restrict__ vt_o, unsigned short* __restrict__ qt_o,
    unsigned short* __restrict__ at_o,
    float* __restrict__ vp_o, float* __restrict__ qp_o, float* __restrict__ ap_o)
{
    int wg = blockIdx.x;
    int tc = wg % 8, b = (wg / 8) & 15, p = wg / 128;
    const float* xs_[6] = {v, q, a, v, q, a};
    const float* Ws_[6] = {Wvt, Wqt, Wat, Wvp, Wqp, Wap};
    const float* bs_[6] = {bvt, bqt, bat, bvp, bqp, bap};

    __shared__ __align__(16) float x_l[12 * D_];   // 12 KB

    int tid = threadIdx.x;
    int t0 = tc * 12;
    const float* x = xs_[p] + (size_t)(b * N_ + t0) * D_;
    for (int i = tid; i < 768; i += 256)
        ((float4*)x_l)[i] = ((const float4*)x)[i];
    __syncthreads();

    int d = tid & 127, tg = tid >> 7;
    const float* W = Ws_[p];
    float bias = bs_[p][d];
    float acc[6];
#pragma unroll
    for (int t = 0; t < 6; t++) acc[t] = bias;

    for (int kb = 0; kb < 32; kb++) {
        int k = kb * 8;
        float w0 = W[(k + 0) * H_ + d], w1 = W[(k + 1) * H_ + d];
        float w2 = W[(k + 2) * H_ + d], w3 = W[(k + 3) * H_ + d];
        float w4 = W[(k + 4) * H_ + d], w5 = W[(k + 5) * H_ + d];
        float w6 = W[(k + 6) * H_ + d], w7 = W[(k + 7) * H_ + d];
#pragma unroll
        for (int t = 0; t < 6; t++) {
            int lt = tg * 6 + t;
            float4 xa = *(const float4*)&x_l[lt * D_ + k];
            float4 xb = *(const float4*)&x_l[lt * D_ + k + 4];
            acc[t] += xa.x * w0 + xa.y * w1 + xa.z * w2 + xa.w * w3
                    + xb.x * w4 + xb.y * w5 + xb.z * w6 + xb.w * w7;
        }
    }

    int trow = b * N_ + t0 + tg * 6;
    if (p < 3) {
        unsigned short* outs[3] = {vt_o, qt_o, at_o};
        unsigned short* o = outs[p];
#pragma unroll
        for (int t = 0; t < 6; t++)
            o[(trow + t) * H_ + d] = f2bf(fmaxf(acc[t], 0.f));   // FCNet relu
    } else {
        float* outs[3] = {vp_o, qp_o, ap_o};
        float* o = outs[p - 3];
#pragma unroll
        for (int t = 0; t < 6; t++) o[(trow + t) * H_ + d] = acc[t];
    }
}

// ---------------------------------------------------------------------------
// Kernel 2 (R9): logits + exp + marginals. WG = (b, vc of CV=4, g), grid 768.
// Stage qg = qt*Wg[:,g] (A operand) and raw at in LDS ONCE; per v, B frags =
// ds_read(at_l) * vt8[v]. Zero mid-loop barriers; marginal halves written
// straight to global partial buffers. E_qa partials bf16 coalesced.
// ---------------------------------------------------------------------------
__global__ __launch_bounds__(256) void k_logits(
    const unsigned short* __restrict__ vt, const unsigned short* __restrict__ qt,
    const unsigned short* __restrict__ at, const float* __restrict__ Wg,
    float* __restrict__ Evq_part, float* __restrict__ Eva_part,
    unsigned short* __restrict__ E_qa_part)
{
    int bid = blockIdx.x;
    int g = bid & 1, vc = (bid >> 1) % NCH, b = bid / (2 * NCH);
    int tid = threadIdx.x;

    __shared__ __align__(16) unsigned short qg_l[N_ * PAD];  // qt*Wg[:,g]
    __shared__ __align__(16) unsigned short at_l[N_ * PAD];  // raw at

    const unsigned short* qtb = qt + (size_t)b * N_ * H_;
    const unsigned short* atb = at + (size_t)b * N_ * H_;

    for (int it = 0; it < 12; it++) {
        int i = tid + it * 256;
        int e = i * 4, t = e >> 7, h = e & 127;
        ushort4 qv = *(const ushort4*)&qtb[e];
        float w0 = Wg[(h + 0) * 2 + g], w1 = Wg[(h + 1) * 2 + g];
        float w2 = Wg[(h + 2) * 2 + g], w3 = Wg[(h + 3) * 2 + g];
        ushort4 o;
        o.x = f2bf(bf2f(qv.x) * w0);
        o.y = f2bf(bf2f(qv.y) * w1);
        o.z = f2bf(bf2f(qv.z) * w2);
        o.w = f2bf(bf2f(qv.w) * w3);
        *(ushort4*)&qg_l[t * PAD + h] = o;
        *(ushort4*)&at_l[t * PAD + h] = *(const ushort4*)&atb[e];
    }
    __syncthreads();   // the only barrier

    int wave = tid >> 6, lane = tid & 63, quad = lane >> 4, l15 = lane & 15;
    int qi0 = (wave >> 1) * 3, aj0 = (wave & 1) * 3;

    float eqa[3][3][4];
#pragma unroll
    for (int i = 0; i < 3; i++)
#pragma unroll
        for (int j = 0; j < 3; j++)
#pragma unroll
            for (int r = 0; r < 4; r++) eqa[i][j][r] = 0.f;

    for (int vl = 0; vl < CV; vl++) {
        int vrow = vc * CV + vl;
        const unsigned short* vrp = vt + ((size_t)b * N_ + vrow) * H_;

        f32x4_t acc[3][3];
#pragma unroll
        for (int i = 0; i < 3; i++)
#pragma unroll
            for (int j = 0; j < 3; j++)
                acc[i][j] = (f32x4_t){0.f, 0.f, 0.f, 0.f};

#pragma unroll
        for (int ks = 0; ks < 4; ks++) {
            bf16x8_t v8 = *(const bf16x8_t*)&vrp[ks * 32 + quad * 8];
            float vtf[8];
#pragma unroll
            for (int j = 0; j < 8; j++) vtf[j] = bf2f((unsigned short)v8[j]);
            bf16x8_t af[3], bfr[3];
#pragma unroll
            for (int i = 0; i < 3; i++)
                af[i] = *(const bf16x8_t*)&qg_l[((qi0 + i) * 16 + l15) * PAD + ks * 32 + quad * 8];
#pragma unroll
            for (int jt = 0; jt < 3; jt++) {
                bf16x8_t raw = *(const bf16x8_t*)&at_l[((aj0 + jt) * 16 + l15) * PAD + ks * 32 + quad * 8];
                bf16x8_t o;
#pragma unroll
                for (int j = 0; j < 8; j++)
                    o[j] = (short)f2bf(bf2f((unsigned short)raw[j]) * vtf[j]);
                bfr[jt] = o;
            }
#pragma unroll
            for (int i = 0; i < 3; i++)
#pragma unroll
                for (int jt = 0; jt < 3; jt++)
                    acc[i][jt] = __builtin_amdgcn_mfma_f32_16x16x32_bf16(af[i], bfr[jt], acc[i][jt], 0, 0, 0);
        }

        // C/D: col(a)=l15, row(q)=quad*4+r  [m89-verified]
        float s[3][4];
        float c[3];
#pragma unroll
        for (int i = 0; i < 3; i++) {
            s[i][0] = 0.f; s[i][1] = 0.f; s[i][2] = 0.f; s[i][3] = 0.f;
        }
        c[0] = 0.f; c[1] = 0.f; c[2] = 0.f;
#pragma unroll
        for (int i = 0; i < 3; i++)
#pragma unroll
            for (int jt = 0; jt < 3; jt++) {
                float e0 = __expf(fminf(fmaxf(acc[i][jt][0], -30.f), 30.f));
                float e1 = __expf(fminf(fmaxf(acc[i][jt][1], -30.f), 30.f));
                float e2 = __expf(fminf(fmaxf(acc[i][jt][2], -30.f), 30.f));
                float e3 = __expf(fminf(fmaxf(acc[i][jt][3], -30.f), 30.f));
                eqa[i][jt][0] += e0; eqa[i][jt][1] += e1;
                eqa[i][jt][2] += e2; eqa[i][jt][3] += e3;
                s[i][0] += e0; s[i][1] += e1; s[i][2] += e2; s[i][3] += e3;
                c[jt] += e0 + e1 + e2 + e3;
            }

        // E_vq half (this wave's 3 a-tiles): reduce over l15, write global
        float* evqp = Evq_part + ((size_t)bid * CV + vl) * 192 + (wave & 1) * 96;
#pragma unroll
        for (int i = 0; i < 3; i++) {
            float s0 = s[i][0], s1 = s[i][1], s2 = s[i][2], s3 = s[i][3];
#pragma unroll
            for (int m = 1; m < 16; m <<= 1) {
                s0 += __shfl_xor(s0, m); s1 += __shfl_xor(s1, m);
                s2 += __shfl_xor(s2, m); s3 += __shfl_xor(s3, m);
            }
            if (l15 == 0) {
                int qr = (qi0 + i) * 16 + quad * 4;
                evqp[qr + 0] = s0; evqp[qr + 1] = s1;
                evqp[qr + 2] = s2; evqp[qr + 3] = s3;
            }
        }
        // E_va half (this wave's 3 q-tiles): reduce over quads, write global
        float* evap = Eva_part + ((size_t)bid * CV + vl) * 192 + (wave >> 1) * 96;
#pragma unroll
        for (int jt = 0; jt < 3; jt++) {
            float cs = c[jt];
            cs += __shfl_xor(cs, 16);
            cs += __shfl_xor(cs, 32);
            if (lane < 16) evap[(aj0 + jt) * 16 + l15] = cs;
        }
    }

    // E_qa partial flush: bf16 coalesced stores, layout [slot][idx][tid]
    unsigned short* Pp = E_qa_part + (size_t)bid * 9216;
#pragma unroll
    for (int i = 0; i < 3; i++)
#pragma unroll
        for (int jt = 0; jt < 3; jt++)
#pragma unroll
            for (int r = 0; r < 4; r++) {
                int idx = (i * 3 + jt) * 4 + r;
                Pp[idx * 256 + tid] = f2bf(eqa[i][jt][r]);
            }
}

// ---------------------------------------------------------------------------
// Kernel 3: reduce bf16 E_qa partials over NCH vc slots. grid = 1152.
// Slot index for (b,vc,g) is bid = b*2*NCH + vc*2 + g.
// ---------------------------------------------------------------------------
__global__ __launch_bounds__(256) void k_reduce(
    const unsigned short* __restrict__ E_qa_part, float* __restrict__ E_qa)
{
    int wg = blockIdx.x;
    int idx = wg % 36, bg = wg / 36;
    int b = bg >> 1, g = bg & 1;
    int tid = threadIdx.x;

    float s = 0.f;
    const unsigned short* Pp = E_qa_part + ((size_t)(b * 2 * NCH + g)) * 9216 + idx * 256 + tid;
#pragma unroll
    for (int vc = 0; vc < NCH; vc++) s += bf2f(Pp[(size_t)vc * 2 * 9216]);

    int wave = tid >> 6, lane = tid & 63, quad = lane >> 4, l15 = lane & 15;
    int qi0 = (wave >> 1) * 3, aj0 = (wave & 1) * 3;
    int i = idx / 12, jt = (idx / 4) % 3, r = idx & 3;
    int qq = (qi0 + i) * 16 + quad * 4 + r;
    int aa = (aj0 + jt) * 16 + l15;
    E_qa[(size_t)bg * 9216 + qq * 96 + aa] = s;
}

// ---------------------------------------------------------------------------
// Kernel 4 (R9): merge E_vq/E_va halves into final marginals + Zinv. grid=32.
// ---------------------------------------------------------------------------
__global__ __launch_bounds__(256) void k_merge(
    const float* __restrict__ Evq_part, const float* __restrict__ Eva_part,
    float* __restrict__ E_vq, float* __restrict__ E_va, float* __restrict__ Zinv)
{
    int b = blockIdx.x >> 1, g = blockIdx.x & 1;
    int tid = threadIdx.x;
    float z = 0.f;
    for (int i = tid; i < 9216; i += 256) {
        int vrow = i / 96, col = i - vrow * 96;
        int vc = vrow / CV, vl = vrow - vc * CV;
        size_t pb = ((size_t)(b * 2 * NCH + vc * 2 + g) * CV + vl) * 192;
        float s1 = Evq_part[pb + col] + Evq_part[pb + 96 + col];
        E_vq[(b * 2 + g) * 9216 + i] = s1;
        z += s1;
        float s2 = Eva_part[pb + col] + Eva_part[pb + 96 + col];
        E_va[(b * 2 + g) * 9216 + i] = s2;
    }
    __shared__ float red[256];
    red[tid] = z;
    __syncthreads();
    for (int s = 128; s > 0; s >>= 1) {
        if (tid < s) red[tid] += red[tid + s];
        __syncthreads();
    }
    if (tid == 0) Zinv[b * 2 + g] = 1.f / fmaxf(red[0], 1e-30f);
}

// ---------------------------------------------------------------------------
// Kernel 5: attended contexts from marginals; c written f32 directly into
// d_out at final positions (c_v/c_q col=g*128+d, c_a col=d*2+g). grid = 576.
// ---------------------------------------------------------------------------
__global__ __launch_bounds__(256) void k_ctx(
    const float* __restrict__ E_vq, const float* __restrict__ E_va,
    const float* __restrict__ E_qa,
    const float* __restrict__ vp, const float* __restrict__ qp,
    const float* __restrict__ ap, const float* __restrict__ Zinv,
    float* __restrict__ out)
{
    int wg = blockIdx.x;
    int tc = wg % 6, g = (wg / 6) & 1, b = (wg / 12) & 15, o = wg / 192;
    int tid = threadIdx.x;
    __shared__ __align__(16) float E1l[16 * 100];
    __shared__ __align__(16) float E2l[16 * 100];
    int t0 = tc * 16;
    const float* Evq = E_vq + (b * 2 + g) * 9216;
    const float* Eva = E_va + (b * 2 + g) * 9216;
    const float* Eqa = E_qa + (b * 2 + g) * 9216;

    if (o == 0) {
        for (int i = tid; i < 1536; i += 256) {
            int t = i / 96, j = i - t * 96;
            E1l[t * 100 + j] = Evq[(t0 + t) * 96 + j];
            E2l[t * 100 + j] = Eva[(t0 + t) * 96 + j];
        }
    } else if (o == 1) {
        for (int i = tid; i < 1536; i += 256) {
            int t = i & 15, j = i >> 4;
            E1l[t * 100 + j] = Evq[j * 96 + t0 + t];
        }
        for (int i = tid; i < 1536; i += 256) {
            int t = i / 96, j = i - t * 96;
            E2l[t * 100 + j] = Eqa[(t0 + t) * 96 + j];
        }
    } else {
        for (int i = tid; i < 1536; i += 256) {
            int t = i & 15, j = i >> 4;
            E1l[t * 100 + j] = Eva[j * 96 + t0 + t];
            E2l[t * 100 + j] = Eqa[j * 96 + t0 + t];
        }
    }
    __syncthreads();

    const float* P1 = ((o == 0) ? qp : vp) + b * N_ * H_;
    const float* P2 = ((o == 2) ? qp : ap) + b * N_ * H_;
    int d = tid & 127, tg = tid >> 7;
    float acc[8] = {0.f, 0.f, 0.f, 0.f, 0.f, 0.f, 0.f, 0.f};
    for (int jb = 0; jb < 24; jb++) {
        int j4 = jb * 4;
        float p10 = P1[(j4 + 0) * H_ + d], p11 = P1[(j4 + 1) * H_ + d];
        float p12 = P1[(j4 + 2) * H_ + d], p13 = P1[(j4 + 3) * H_ + d];
        float p20 = P2[(j4 + 0) * H_ + d], p21 = P2[(j4 + 1) * H_ + d];
        float p22 = P2[(j4 + 2) * H_ + d], p23 = P2[(j4 + 3) * H_ + d];
#pragma unroll
        for (int t8 = 0; t8 < 8; t8++) {
            int t = tg * 8 + t8;
            float4 e1 = *(const float4*)&E1l[t * 100 + j4];
            float4 e2 = *(const float4*)&E2l[t * 100 + j4];
            acc[t8] += e1.x * p10 + e1.y * p11 + e1.z * p12 + e1.w * p13
                     + e2.x * p20 + e2.y * p21 + e2.z * p22 + e2.w * p23;
        }
    }
    float zi = Zinv[b * 2 + g];
    float* ob = out + (size_t)((o * B_ + b) * N_) * 256;
#pragma unroll
    for (int t8 = 0; t8 < 8; t8++) {
        int T = t0 + tg * 8 + t8;
        int col = (o == 2) ? (d * 2 + g) : (g * 128 + d);
        ob[T * 256 + col] = acc[t8] * zi;
    }
}

// ---------------------------------------------------------------------------
// Kernel 6: updated_x = x + c_x @ Wxu + bxu, in place over d_out. grid = 576.
// ---------------------------------------------------------------------------
__global__ __launch_bounds__(256) void k_update(
    const float* __restrict__ v, const float* __restrict__ q,
    const float* __restrict__ a,
    const float* __restrict__ Wvu, const float* __restrict__ bvu,
    const float* __restrict__ Wqu, const float* __restrict__ bqu,
    const float* __restrict__ Wau, const float* __restrict__ bau,
    float* __restrict__ out)
{
    int wg = blockIdx.x;
    int tc = wg % 12, b = (wg / 12) & 15, o = wg / 192;
    int tid = threadIdx.x;
    const float* xs_[3] = {v, q, a};
    const float* Ws_[3] = {Wvu, Wqu, Wau};
    const float* bs_[3] = {bvu, bqu, bau};
    int t0 = tc * 8;

    __shared__ __align__(16) float c_l[8 * 256];
    float* cbase = out + (size_t)((o * B_ + b) * N_ + t0) * 256;
    for (int i = tid; i < 2048; i += 256) c_l[i] = cbase[i];
    __syncthreads();

    const float* W = Ws_[o];
    const float* x = xs_[o] + (size_t)(b * N_ + t0) * 256;
    float bias = bs_[o][tid];
    float acc[8];
#pragma unroll
    for (int t = 0; t < 8; t++) acc[t] = bias + x[t * 256 + tid];

    for (int kb = 0; kb < 64; kb++) {
        int k = kb * 4;
        float w0 = W[(k + 0) * 256 + tid];
        float w1 = W[(k + 1) * 256 + tid];
        float w2 = W[(k + 2) * 256 + tid];
        float w3 = W[(k + 3) * 256 + tid];
#pragma unroll
        for (int t = 0; t < 8; t++) {
            float4 c4 = *(const float4*)&c_l[t * 256 + k];
            acc[t] += c4.x * w0 + c4.y * w1 + c4.z * w2 + c4.w * w3;
        }
    }
#pragma unroll
    for (int t = 0; t < 8; t++) cbase[t * 256 + tid] = acc[t];
}

// ---------------------------------------------------------------------------
extern "C" void kernel_launch(void* const* d_in, const int* in_sizes, int n_in,
                              void* d_out, int out_size, void* d_ws, size_t ws_size,
                              hipStream_t stream)
{
    const float* v   = (const float*)d_in[0];
    const float* q   = (const float*)d_in[1];
    const float* a   = (const float*)d_in[2];
    const float* Wvt = (const float*)d_in[3];
    const float* bvt = (const float*)d_in[4];
    const float* Wqt = (const float*)d_in[5];
    const float* bqt = (const float*)d_in[6];
    const float* Wat = (const float*)d_in[7];
    const float* bat = (const float*)d_in[8];
    const float* Wg  = (const float*)d_in[9];
    const float* Wvp = (const float*)d_in[10];
    const float* bvp = (const float*)d_in[11];
    const float* Wqp = (const float*)d_in[12];
    const float* bqp = (const float*)d_in[13];
    const float* Wap = (const float*)d_in[14];
    const float* bap = (const float*)d_in[15];
    const float* Wvu = (const float*)d_in[16];
    const float* bvu = (const float*)d_in[17];
    const float* Wqu = (const float*)d_in[18];
    const float* bqu = (const float*)d_in[19];
    const float* Wau = (const float*)d_in[20];
    const float* bau = (const float*)d_in[21];

    char* ws = (char*)d_ws;
    size_t off = 0;
    auto alloc = [&](size_t bytes) {
        char* p = ws + off;
        off += (bytes + 255) & ~(size_t)255;
        return (void*)p;
    };
    unsigned short* vt = (unsigned short*)alloc((size_t)B_ * N_ * H_ * 2);
    unsigned short* qt = (unsigned short*)alloc((size_t)B_ * N_ * H_ * 2);
    unsigned short* at = (unsigned short*)alloc((size_t)B_ * N_ * H_ * 2);
    float* vpb  = (float*)alloc((size_t)B_ * N_ * H_ * 4);
    float* qpb  = (float*)alloc((size_t)B_ * N_ * H_ * 4);
    float* apb  = (float*)alloc((size_t)B_ * N_ * H_ * 4);
    float* E_vq = (float*)alloc((size_t)B_ * 2 * 9216 * 4);
    float* E_va = (float*)alloc((size_t)B_ * 2 * 9216 * 4);
    float* E_qa = (float*)alloc((size_t)B_ * 2 * 9216 * 4);
    float* Zinv = (float*)alloc(256);
    float* Evq_part = (float*)alloc((size_t)768 * CV * 192 * 4);   // 2.36 MB
    float* Eva_part = (float*)alloc((size_t)768 * CV * 192 * 4);   // 2.36 MB
    unsigned short* E_qa_part =
        (unsigned short*)alloc((size_t)B_ * NCH * 2 * 9216 * 2);   // 14.2 MB bf16
    // total ~26 MB

    k_proj<<<768, 256, 0, stream>>>(v, q, a, Wvt, bvt, Wqt, bqt, Wat, bat,
                                    Wvp, bvp, Wqp, bqp, Wap, bap,
                                    vt, qt, at, vpb, qpb, apb);
    k_logits<<<B_ * NCH * 2, 256, 0, stream>>>(vt, qt, at, Wg,
                                               Evq_part, Eva_part, E_qa_part);
    k_reduce<<<1152, 256, 0, stream>>>(E_qa_part, E_qa);
    k_merge<<<32, 256, 0, stream>>>(Evq_part, Eva_part, E_vq, E_va, Zinv);
    k_ctx<<<576, 256, 0, stream>>>(E_vq, E_va, E_qa, vpb, qpb, apb, Zinv,
                                   (float*)d_out);
    k_update<<<576, 256, 0, stream>>>(v, q, a, Wvu, bvu, Wqu, bqu, Wau, bau,
                                      (float*)d_out);
}

// Round 10
// 206.095 us; speedup vs baseline: 1.3297x; 1.0922x over previous
//
#include <hip/hip_runtime.h>

// TriAttention factorized implementation — all-f32 I/O, fp16 MFMA logits.
// dims: B=16, N(v,q,a)=96, D=256, H=128, G=2
// l[v,q,a,g] = sum_h qt[q,h] * (at[a,h]*vt[v,h]*Wg[h,g]); contractions
// factor through pairwise marginals of softmax(l) (p never materialized).
// R10: logit operands in FP16. A = raw qt (no scaling!); B = at * vtg[v,g]
// where vtg = vt*Wg precomputed in k_proj. B-scale via v_pk_mul_f16
// (hardware packed mul) instead of R9's ~6-inst/elem software bf16 repack.
// Barrier-free v-loop, marginal halves -> global partials (R9 structure).

#define B_  16
#define N_  96
#define D_  256
#define H_  128
#define CV  4     // v rows per k_logits workgroup
#define NCH 24    // v-chunks = 96/CV
#define PAD 136   // LDS row stride in f16 elems (272 B, 16B-aligned)

typedef _Float16 f16x8 __attribute__((ext_vector_type(8)));
typedef float f32x4_t  __attribute__((ext_vector_type(4)));

__device__ __forceinline__ float bf2f(unsigned short u) {
    union { unsigned u32; float f; } x;
    x.u32 = ((unsigned)u) << 16;
    return x.f;
}

// ---------------------------------------------------------------------------
// Kernel 1: six projections x@W+b -> [B,96,128].
// p=0 (v-tucker): writes vtg[b,v,g,h] = relu(vt)*Wg[h,g] as f16 (both g).
// p=1,2 (q/a-tucker): relu'd f16. p>=3 (value projections): f32.
// grid = 768 (3 WG/CU), 12 tokens/WG.
// ---------------------------------------------------------------------------
__global__ __launch_bounds__(256) void k_proj(
    const float* __restrict__ v, const float* __restrict__ q,
    const float* __restrict__ a,
    const float* __restrict__ Wvt, const float* __restrict__ bvt,
    const float* __restrict__ Wqt, const float* __restrict__ bqt,
    const float* __restrict__ Wat, const float* __restrict__ bat,
    const float* __restrict__ Wvp, const float* __restrict__ bvp,
    const float* __restrict__ Wqp, const float* __restrict__ bqp,
    const float* __restrict__ Wap, const float* __restrict__ bap,
    const float* __restrict__ Wg,
    _Float16* __restrict__ vtg_o, _Float16* __restrict__ qt_o,
    _Float16* __restrict__ at_o,
    float* __restrict__ vp_o, float* __restrict__ qp_o, float* __restrict__ ap_o)
{
    int wg = blockIdx.x;
    int tc = wg % 8, b = (wg / 8) & 15, p = wg / 128;
    const float* xs_[6] = {v, q, a, v, q, a};
    const float* Ws_[6] = {Wvt, Wqt, Wat, Wvp, Wqp, Wap};
    const float* bs_[6] = {bvt, bqt, bat, bvp, bqp, bap};

    __shared__ __align__(16) float x_l[12 * D_];   // 12 KB

    int tid = threadIdx.x;
    int t0 = tc * 12;
    const float* x = xs_[p] + (size_t)(b * N_ + t0) * D_;
    for (int i = tid; i < 768; i += 256)
        ((float4*)x_l)[i] = ((const float4*)x)[i];
    __syncthreads();

    int d = tid & 127, tg = tid >> 7;
    const float* W = Ws_[p];
    float bias = bs_[p][d];
    float acc[6];
#pragma unroll
    for (int t = 0; t < 6; t++) acc[t] = bias;

    for (int kb = 0; kb < 32; kb++) {
        int k = kb * 8;
        float w0 = W[(k + 0) * H_ + d], w1 = W[(k + 1) * H_ + d];
        float w2 = W[(k + 2) * H_ + d], w3 = W[(k + 3) * H_ + d];
        float w4 = W[(k + 4) * H_ + d], w5 = W[(k + 5) * H_ + d];
        float w6 = W[(k + 6) * H_ + d], w7 = W[(k + 7) * H_ + d];
#pragma unroll
        for (int t = 0; t < 6; t++) {
            int lt = tg * 6 + t;
            float4 xa = *(const float4*)&x_l[lt * D_ + k];
            float4 xb = *(const float4*)&x_l[lt * D_ + k + 4];
            acc[t] += xa.x * w0 + xa.y * w1 + xa.z * w2 + xa.w * w3
                    + xb.x * w4 + xb.y * w5 + xb.z * w6 + xb.w * w7;
        }
    }

    int trow = b * N_ + t0 + tg * 6;
    if (p == 0) {
        float wg0 = Wg[d * 2 + 0], wg1 = Wg[d * 2 + 1];
#pragma unroll
        for (int t = 0; t < 6; t++) {
            float r = fmaxf(acc[t], 0.f);                     // FCNet relu
            _Float16* vg = vtg_o + (size_t)(trow + t) * 2 * H_;
            vg[d]      = (_Float16)(r * wg0);
            vg[H_ + d] = (_Float16)(r * wg1);
        }
    } else if (p < 3) {
        _Float16* o = (p == 1) ? qt_o : at_o;
#pragma unroll
        for (int t = 0; t < 6; t++)
            o[(trow + t) * H_ + d] = (_Float16)fmaxf(acc[t], 0.f);
    } else {
        float* outs[3] = {vp_o, qp_o, ap_o};
        float* o = outs[p - 3];
#pragma unroll
        for (int t = 0; t < 6; t++) o[(trow + t) * H_ + d] = acc[t];
    }
}

// ---------------------------------------------------------------------------
// Kernel 2 (R10): logits + exp + marginals, fp16 operands. WG = (b,vc,g),
// grid 768. Stage RAW qt (A) and RAW at in LDS once; per v: B frags =
// ds_read(at_l) * vtg8 via v_pk_mul_f16. Zero mid-loop barriers; marginal
// halves -> global partials; E_qa partials bf16 coalesced.
// ---------------------------------------------------------------------------
__global__ __launch_bounds__(256) void k_logits(
    const _Float16* __restrict__ vtg, const _Float16* __restrict__ qt,
    const _Float16* __restrict__ at,
    float* __restrict__ Evq_part, float* __restrict__ Eva_part,
    unsigned short* __restrict__ E_qa_part)
{
    int bid = blockIdx.x;
    int g = bid & 1, vc = (bid >> 1) % NCH, b = bid / (2 * NCH);
    int tid = threadIdx.x;

    __shared__ __align__(16) _Float16 qt_l[N_ * PAD];  // raw qt (A operand)
    __shared__ __align__(16) _Float16 at_l[N_ * PAD];  // raw at (B base)

    const _Float16* qtb = qt + (size_t)b * N_ * H_;
    const _Float16* atb = at + (size_t)b * N_ * H_;

    for (int it = 0; it < 12; it++) {
        int i = tid + it * 256;
        int e = i * 4, t = e >> 7, h = e & 127;
        *(ushort4*)&qt_l[t * PAD + h] = *(const ushort4*)&qtb[e];
        *(ushort4*)&at_l[t * PAD + h] = *(const ushort4*)&atb[e];
    }
    __syncthreads();   // the only barrier

    int wave = tid >> 6, lane = tid & 63, quad = lane >> 4, l15 = lane & 15;
    int qi0 = (wave >> 1) * 3, aj0 = (wave & 1) * 3;

    float eqa[3][3][4];
#pragma unroll
    for (int i = 0; i < 3; i++)
#pragma unroll
        for (int j = 0; j < 3; j++)
#pragma unroll
            for (int r = 0; r < 4; r++) eqa[i][j][r] = 0.f;

    for (int vl = 0; vl < CV; vl++) {
        int vrow = vc * CV + vl;
        const _Float16* vgp = vtg + ((size_t)(b * N_ + vrow) * 2 + g) * H_;

        f32x4_t acc[3][3];
#pragma unroll
        for (int i = 0; i < 3; i++)
#pragma unroll
            for (int j = 0; j < 3; j++)
                acc[i][j] = (f32x4_t){0.f, 0.f, 0.f, 0.f};

#pragma unroll
        for (int ks = 0; ks < 4; ks++) {
            f16x8 v8 = *(const f16x8*)&vgp[ks * 32 + quad * 8];
            f16x8 af[3], bfr[3];
#pragma unroll
            for (int i = 0; i < 3; i++)
                af[i] = *(const f16x8*)&qt_l[((qi0 + i) * 16 + l15) * PAD + ks * 32 + quad * 8];
#pragma unroll
            for (int jt = 0; jt < 3; jt++) {
                f16x8 raw = *(const f16x8*)&at_l[((aj0 + jt) * 16 + l15) * PAD + ks * 32 + quad * 8];
                bfr[jt] = raw * v8;                 // 4x v_pk_mul_f16
            }
#pragma unroll
            for (int i = 0; i < 3; i++)
#pragma unroll
                for (int jt = 0; jt < 3; jt++)
                    acc[i][jt] = __builtin_amdgcn_mfma_f32_16x16x32_f16(af[i], bfr[jt], acc[i][jt], 0, 0, 0);
        }

        // C/D: col(a)=l15, row(q)=quad*4+r  [m89-verified, dtype-independent]
        float s[3][4];
        float c[3];
#pragma unroll
        for (int i = 0; i < 3; i++) {
            s[i][0] = 0.f; s[i][1] = 0.f; s[i][2] = 0.f; s[i][3] = 0.f;
        }
        c[0] = 0.f; c[1] = 0.f; c[2] = 0.f;
#pragma unroll
        for (int i = 0; i < 3; i++)
#pragma unroll
            for (int jt = 0; jt < 3; jt++) {
                float e0 = __expf(fminf(fmaxf(acc[i][jt][0], -30.f), 30.f));
                float e1 = __expf(fminf(fmaxf(acc[i][jt][1], -30.f), 30.f));
                float e2 = __expf(fminf(fmaxf(acc[i][jt][2], -30.f), 30.f));
                float e3 = __expf(fminf(fmaxf(acc[i][jt][3], -30.f), 30.f));
                eqa[i][jt][0] += e0; eqa[i][jt][1] += e1;
                eqa[i][jt][2] += e2; eqa[i][jt][3] += e3;
                s[i][0] += e0; s[i][1] += e1; s[i][2] += e2; s[i][3] += e3;
                c[jt] += e0 + e1 + e2 + e3;
            }

        // E_vq half (this wave's 3 a-tiles): reduce over l15, write global
        float* evqp = Evq_part + ((size_t)bid * CV + vl) * 192 + (wave & 1) * 96;
#pragma unroll
        for (int i = 0; i < 3; i++) {
            float s0 = s[i][0], s1 = s[i][1], s2 = s[i][2], s3 = s[i][3];
#pragma unroll
            for (int m = 1; m < 16; m <<= 1) {
                s0 += __shfl_xor(s0, m); s1 += __shfl_xor(s1, m);
                s2 += __shfl_xor(s2, m); s3 += __shfl_xor(s3, m);
            }
            if (l15 == 0) {
                int qr = (qi0 + i) * 16 + quad * 4;
                evqp[qr + 0] = s0; evqp[qr + 1] = s1;
                evqp[qr + 2] = s2; evqp[qr + 3] = s3;
            }
        }
        // E_va half (this wave's 3 q-tiles): reduce over quads, write global
        float* evap = Eva_part + ((size_t)bid * CV + vl) * 192 + (wave >> 1) * 96;
#pragma unroll
        for (int jt = 0; jt < 3; jt++) {
            float cs = c[jt];
            cs += __shfl_xor(cs, 16);
            cs += __shfl_xor(cs, 32);
            if (lane < 16) evap[(aj0 + jt) * 16 + l15] = cs;
        }
    }

    // E_qa partial flush: bf16 coalesced stores, layout [slot][idx][tid]
    unsigned short* Pp = E_qa_part + (size_t)bid * 9216;
#pragma unroll
    for (int i = 0; i < 3; i++)
#pragma unroll
        for (int jt = 0; jt < 3; jt++)
#pragma unroll
            for (int r = 0; r < 4; r++) {
                int idx = (i * 3 + jt) * 4 + r;
                union { float f; unsigned u; } x;
                x.f = eqa[i][jt][r];
                unsigned rr = x.u + 0x7fffu + ((x.u >> 16) & 1u);
                Pp[idx * 256 + tid] = (unsigned short)(rr >> 16);
            }
}

// ---------------------------------------------------------------------------
// Kernel 3: reduce bf16 E_qa partials over NCH vc slots. grid = 1152.
// ---------------------------------------------------------------------------
__global__ __launch_bounds__(256) void k_reduce(
    const unsigned short* __restrict__ E_qa_part, float* __restrict__ E_qa)
{
    int wg = blockIdx.x;
    int idx = wg % 36, bg = wg / 36;
    int b = bg >> 1, g = bg & 1;
    int tid = threadIdx.x;

    float s = 0.f;
    const unsigned short* Pp = E_qa_part + ((size_t)(b * 2 * NCH + g)) * 9216 + idx * 256 + tid;
#pragma unroll
    for (int vc = 0; vc < NCH; vc++) s += bf2f(Pp[(size_t)vc * 2 * 9216]);

    int wave = tid >> 6, lane = tid & 63, quad = lane >> 4, l15 = lane & 15;
    int qi0 = (wave >> 1) * 3, aj0 = (wave & 1) * 3;
    int i = idx / 12, jt = (idx / 4) % 3, r = idx & 3;
    int qq = (qi0 + i) * 16 + quad * 4 + r;
    int aa = (aj0 + jt) * 16 + l15;
    E_qa[(size_t)bg * 9216 + qq * 96 + aa] = s;
}

// ---------------------------------------------------------------------------
// Kernel 4: merge E_vq/E_va halves into final marginals + Zinv. grid = 32.
// ---------------------------------------------------------------------------
__global__ __launch_bounds__(256) void k_merge(
    const float* __restrict__ Evq_part, const float* __restrict__ Eva_part,
    float* __restrict__ E_vq, float* __restrict__ E_va, float* __restrict__ Zinv)
{
    int b = blockIdx.x >> 1, g = blockIdx.x & 1;
    int tid = threadIdx.x;
    float z = 0.f;
    for (int i = tid; i < 9216; i += 256) {
        int vrow = i / 96, col = i - vrow * 96;
        int vc = vrow / CV, vl = vrow - vc * CV;
        size_t pb = ((size_t)(b * 2 * NCH + vc * 2 + g) * CV + vl) * 192;
        float s1 = Evq_part[pb + col] + Evq_part[pb + 96 + col];
        E_vq[(b * 2 + g) * 9216 + i] = s1;
        z += s1;
        float s2 = Eva_part[pb + col] + Eva_part[pb + 96 + col];
        E_va[(b * 2 + g) * 9216 + i] = s2;
    }
    __shared__ float red[256];
    red[tid] = z;
    __syncthreads();
    for (int s = 128; s > 0; s >>= 1) {
        if (tid < s) red[tid] += red[tid + s];
        __syncthreads();
    }
    if (tid == 0) Zinv[b * 2 + g] = 1.f / fmaxf(red[0], 1e-30f);
}

// ---------------------------------------------------------------------------
// Kernel 5: attended contexts from marginals; c written f32 directly into
// d_out at final positions (c_v/c_q col=g*128+d, c_a col=d*2+g). grid = 576.
// ---------------------------------------------------------------------------
__global__ __launch_bounds__(256) void k_ctx(
    const float* __restrict__ E_vq, const float* __restrict__ E_va,
    const float* __restrict__ E_qa,
    const float* __restrict__ vp, const float* __restrict__ qp,
    const float* __restrict__ ap, const float* __restrict__ Zinv,
    float* __restrict__ out)
{
    int wg = blockIdx.x;
    int tc = wg % 6, g = (wg / 6) & 1, b = (wg / 12) & 15, o = wg / 192;
    int tid = threadIdx.x;
    __shared__ __align__(16) float E1l[16 * 100];
    __shared__ __align__(16) float E2l[16 * 100];
    int t0 = tc * 16;
    const float* Evq = E_vq + (b * 2 + g) * 9216;
    const float* Eva = E_va + (b * 2 + g) * 9216;
    const float* Eqa = E_qa + (b * 2 + g) * 9216;

    if (o == 0) {
        for (int i = tid; i < 1536; i += 256) {
            int t = i / 96, j = i - t * 96;
            E1l[t * 100 + j] = Evq[(t0 + t) * 96 + j];
            E2l[t * 100 + j] = Eva[(t0 + t) * 96 + j];
        }
    } else if (o == 1) {
        for (int i = tid; i < 1536; i += 256) {
            int t = i & 15, j = i >> 4;
            E1l[t * 100 + j] = Evq[j * 96 + t0 + t];
        }
        for (int i = tid; i < 1536; i += 256) {
            int t = i / 96, j = i - t * 96;
            E2l[t * 100 + j] = Eqa[(t0 + t) * 96 + j];
        }
    } else {
        for (int i = tid; i < 1536; i += 256) {
            int t = i & 15, j = i >> 4;
            E1l[t * 100 + j] = Eva[j * 96 + t0 + t];
            E2l[t * 100 + j] = Eqa[j * 96 + t0 + t];
        }
    }
    __syncthreads();

    const float* P1 = ((o == 0) ? qp : vp) + b * N_ * H_;
    const float* P2 = ((o == 2) ? qp : ap) + b * N_ * H_;
    int d = tid & 127, tg = tid >> 7;
    float acc[8] = {0.f, 0.f, 0.f, 0.f, 0.f, 0.f, 0.f, 0.f};
    for (int jb = 0; jb < 24; jb++) {
        int j4 = jb * 4;
        float p10 = P1[(j4 + 0) * H_ + d], p11 = P1[(j4 + 1) * H_ + d];
        float p12 = P1[(j4 + 2) * H_ + d], p13 = P1[(j4 + 3) * H_ + d];
        float p20 = P2[(j4 + 0) * H_ + d], p21 = P2[(j4 + 1) * H_ + d];
        float p22 = P2[(j4 + 2) * H_ + d], p23 = P2[(j4 + 3) * H_ + d];
#pragma unroll
        for (int t8 = 0; t8 < 8; t8++) {
            int t = tg * 8 + t8;
            float4 e1 = *(const float4*)&E1l[t * 100 + j4];
            float4 e2 = *(const float4*)&E2l[t * 100 + j4];
            acc[t8] += e1.x * p10 + e1.y * p11 + e1.z * p12 + e1.w * p13
                     + e2.x * p20 + e2.y * p21 + e2.z * p22 + e2.w * p23;
        }
    }
    float zi = Zinv[b * 2 + g];
    float* ob = out + (size_t)((o * B_ + b) * N_) * 256;
#pragma unroll
    for (int t8 = 0; t8 < 8; t8++) {
        int T = t0 + tg * 8 + t8;
        int col = (o == 2) ? (d * 2 + g) : (g * 128 + d);
        ob[T * 256 + col] = acc[t8] * zi;
    }
}

// ---------------------------------------------------------------------------
// Kernel 6: updated_x = x + c_x @ Wxu + bxu, in place over d_out. grid = 576.
// ---------------------------------------------------------------------------
__global__ __launch_bounds__(256) void k_update(
    const float* __restrict__ v, const float* __restrict__ q,
    const float* __restrict__ a,
    const float* __restrict__ Wvu, const float* __restrict__ bvu,
    const float* __restrict__ Wqu, const float* __restrict__ bqu,
    const float* __restrict__ Wau, const float* __restrict__ bau,
    float* __restrict__ out)
{
    int wg = blockIdx.x;
    int tc = wg % 12, b = (wg / 12) & 15, o = wg / 192;
    int tid = threadIdx.x;
    const float* xs_[3] = {v, q, a};
    const float* Ws_[3] = {Wvu, Wqu, Wau};
    const float* bs_[3] = {bvu, bqu, bau};
    int t0 = tc * 8;

    __shared__ __align__(16) float c_l[8 * 256];
    float* cbase = out + (size_t)((o * B_ + b) * N_ + t0) * 256;
    for (int i = tid; i < 2048; i += 256) c_l[i] = cbase[i];
    __syncthreads();

    const float* W = Ws_[o];
    const float* x = xs_[o] + (size_t)(b * N_ + t0) * 256;
    float bias = bs_[o][tid];
    float acc[8];
#pragma unroll
    for (int t = 0; t < 8; t++) acc[t] = bias + x[t * 256 + tid];

    for (int kb = 0; kb < 64; kb++) {
        int k = kb * 4;
        float w0 = W[(k + 0) * 256 + tid];
        float w1 = W[(k + 1) * 256 + tid];
        float w2 = W[(k + 2) * 256 + tid];
        float w3 = W[(k + 3) * 256 + tid];
#pragma unroll
        for (int t = 0; t < 8; t++) {
            float4 c4 = *(const float4*)&c_l[t * 256 + k];
            acc[t] += c4.x * w0 + c4.y * w1 + c4.z * w2 + c4.w * w3;
        }
    }
#pragma unroll
    for (int t = 0; t < 8; t++) cbase[t * 256 + tid] = acc[t];
}

// ---------------------------------------------------------------------------
extern "C" void kernel_launch(void* const* d_in, const int* in_sizes, int n_in,
                              void* d_out, int out_size, void* d_ws, size_t ws_size,
                              hipStream_t stream)
{
    const float* v   = (const float*)d_in[0];
    const float* q   = (const float*)d_in[1];
    const float* a   = (const float*)d_in[2];
    const float* Wvt = (const float*)d_in[3];
    const float* bvt = (const float*)d_in[4];
    const float* Wqt = (const float*)d_in[5];
    const float* bqt = (const float*)d_in[6];
    const float* Wat = (const float*)d_in[7];
    const float* bat = (const float*)d_in[8];
    const float* Wg  = (const float*)d_in[9];
    const float* Wvp = (const float*)d_in[10];
    const float* bvp = (const float*)d_in[11];
    const float* Wqp = (const float*)d_in[12];
    const float* bqp = (const float*)d_in[13];
    const float* Wap = (const float*)d_in[14];
    const float* bap = (const float*)d_in[15];
    const float* Wvu = (const float*)d_in[16];
    const float* bvu = (const float*)d_in[17];
    const float* Wqu = (const float*)d_in[18];
    const float* bqu = (const float*)d_in[19];
    const float* Wau = (const float*)d_in[20];
    const float* bau = (const float*)d_in[21];

    char* ws = (char*)d_ws;
    size_t off = 0;
    auto alloc = [&](size_t bytes) {
        char* p = ws + off;
        off += (bytes + 255) & ~(size_t)255;
        return (void*)p;
    };
    _Float16* vtg = (_Float16*)alloc((size_t)B_ * N_ * 2 * H_ * 2);   // 786 KB
    _Float16* qt  = (_Float16*)alloc((size_t)B_ * N_ * H_ * 2);
    _Float16* at  = (_Float16*)alloc((size_t)B_ * N_ * H_ * 2);
    float* vpb  = (float*)alloc((size_t)B_ * N_ * H_ * 4);
    float* qpb  = (float*)alloc((size_t)B_ * N_ * H_ * 4);
    float* apb  = (float*)alloc((size_t)B_ * N_ * H_ * 4);
    float* E_vq = (float*)alloc((size_t)B_ * 2 * 9216 * 4);
    float* E_va = (float*)alloc((size_t)B_ * 2 * 9216 * 4);
    float* E_qa = (float*)alloc((size_t)B_ * 2 * 9216 * 4);
    float* Zinv = (float*)alloc(256);
    float* Evq_part = (float*)alloc((size_t)768 * CV * 192 * 4);   // 2.36 MB
    float* Eva_part = (float*)alloc((size_t)768 * CV * 192 * 4);   // 2.36 MB
    unsigned short* E_qa_part =
        (unsigned short*)alloc((size_t)B_ * NCH * 2 * 9216 * 2);   // 14.2 MB bf16
    // total ~26 MB

    k_proj<<<768, 256, 0, stream>>>(v, q, a, Wvt, bvt, Wqt, bqt, Wat, bat,
                                    Wvp, bvp, Wqp, bqp, Wap, bap, Wg,
                                    vtg, qt, at, vpb, qpb, apb);
    k_logits<<<B_ * NCH * 2, 256, 0, stream>>>(vtg, qt, at,
                                               Evq_part, Eva_part, E_qa_part);
    k_reduce<<<1152, 256, 0, stream>>>(E_qa_part, E_qa);
    k_merge<<<32, 256, 0, stream>>>(Evq_part, Eva_part, E_vq, E_va, Zinv);
    k_ctx<<<576, 256, 0, stream>>>(E_vq, E_va, E_qa, vpb, qpb, apb, Zinv,
                                   (float*)d_out);
    k_update<<<576, 256, 0, stream>>>(v, q, a, Wvu, bvu, Wqu, bqu, Wau, bau,
                                      (float*)d_out);
}

// Round 11
// 199.317 us; speedup vs baseline: 1.3749x; 1.0340x over previous
//
#include <hip/hip_runtime.h>

// TriAttention factorized implementation — all-f32 I/O, fp16 MFMA logits.
// dims: B=16, N(v,q,a)=96, D=256, H=128, G=2
// l[v,q,a,g] = sum_h qt[q,h] * (at[a,h]*vt[v,h]*Wg[h,g]); contractions
// factor through pairwise marginals of softmax(l) (p never materialized).
// R11: 4-dispatch pipeline. k_mid = reduce+merge fused (branch on block);
// k_ctxup = ctx+update fused, c LDS-resident (no d_out round-trip).

#define B_  16
#define N_  96
#define D_  256
#define H_  128
#define CV  4     // v rows per k_logits workgroup
#define NCH 24    // v-chunks = 96/CV
#define PAD 136   // LDS row stride in f16 elems (272 B, 16B-aligned)

typedef _Float16 f16x8 __attribute__((ext_vector_type(8)));
typedef float f32x4_t  __attribute__((ext_vector_type(4)));

__device__ __forceinline__ float bf2f(unsigned short u) {
    union { unsigned u32; float f; } x;
    x.u32 = ((unsigned)u) << 16;
    return x.f;
}

// ---------------------------------------------------------------------------
// Kernel 1: six projections x@W+b -> [B,96,128].
// p=0: vtg[b,v,g,h] = relu(vt)*Wg[h,g] f16 (both g). p=1,2: relu'd f16.
// p>=3: value projections f32. grid = 768 (3 WG/CU), 12 tokens/WG.
// ---------------------------------------------------------------------------
__global__ __launch_bounds__(256) void k_proj(
    const float* __restrict__ v, const float* __restrict__ q,
    const float* __restrict__ a,
    const float* __restrict__ Wvt, const float* __restrict__ bvt,
    const float* __restrict__ Wqt, const float* __restrict__ bqt,
    const float* __restrict__ Wat, const float* __restrict__ bat,
    const float* __restrict__ Wvp, const float* __restrict__ bvp,
    const float* __restrict__ Wqp, const float* __restrict__ bqp,
    const float* __restrict__ Wap, const float* __restrict__ bap,
    const float* __restrict__ Wg,
    _Float16* __restrict__ vtg_o, _Float16* __restrict__ qt_o,
    _Float16* __restrict__ at_o,
    float* __restrict__ vp_o, float* __restrict__ qp_o, float* __restrict__ ap_o)
{
    int wg = blockIdx.x;
    int tc = wg % 8, b = (wg / 8) & 15, p = wg / 128;
    const float* xs_[6] = {v, q, a, v, q, a};
    const float* Ws_[6] = {Wvt, Wqt, Wat, Wvp, Wqp, Wap};
    const float* bs_[6] = {bvt, bqt, bat, bvp, bqp, bap};

    __shared__ __align__(16) float x_l[12 * D_];   // 12 KB

    int tid = threadIdx.x;
    int t0 = tc * 12;
    const float* x = xs_[p] + (size_t)(b * N_ + t0) * D_;
    for (int i = tid; i < 768; i += 256)
        ((float4*)x_l)[i] = ((const float4*)x)[i];
    __syncthreads();

    int d = tid & 127, tg = tid >> 7;
    const float* W = Ws_[p];
    float bias = bs_[p][d];
    float acc[6];
#pragma unroll
    for (int t = 0; t < 6; t++) acc[t] = bias;

    for (int kb = 0; kb < 32; kb++) {
        int k = kb * 8;
        float w0 = W[(k + 0) * H_ + d], w1 = W[(k + 1) * H_ + d];
        float w2 = W[(k + 2) * H_ + d], w3 = W[(k + 3) * H_ + d];
        float w4 = W[(k + 4) * H_ + d], w5 = W[(k + 5) * H_ + d];
        float w6 = W[(k + 6) * H_ + d], w7 = W[(k + 7) * H_ + d];
#pragma unroll
        for (int t = 0; t < 6; t++) {
            int lt = tg * 6 + t;
            float4 xa = *(const float4*)&x_l[lt * D_ + k];
            float4 xb = *(const float4*)&x_l[lt * D_ + k + 4];
            acc[t] += xa.x * w0 + xa.y * w1 + xa.z * w2 + xa.w * w3
                    + xb.x * w4 + xb.y * w5 + xb.z * w6 + xb.w * w7;
        }
    }

    int trow = b * N_ + t0 + tg * 6;
    if (p == 0) {
        float wg0 = Wg[d * 2 + 0], wg1 = Wg[d * 2 + 1];
#pragma unroll
        for (int t = 0; t < 6; t++) {
            float r = fmaxf(acc[t], 0.f);                     // FCNet relu
            _Float16* vg = vtg_o + (size_t)(trow + t) * 2 * H_;
            vg[d]      = (_Float16)(r * wg0);
            vg[H_ + d] = (_Float16)(r * wg1);
        }
    } else if (p < 3) {
        _Float16* o = (p == 1) ? qt_o : at_o;
#pragma unroll
        for (int t = 0; t < 6; t++)
            o[(trow + t) * H_ + d] = (_Float16)fmaxf(acc[t], 0.f);
    } else {
        float* outs[3] = {vp_o, qp_o, ap_o};
        float* o = outs[p - 3];
#pragma unroll
        for (int t = 0; t < 6; t++) o[(trow + t) * H_ + d] = acc[t];
    }
}

// ---------------------------------------------------------------------------
// Kernel 2: logits + exp + marginals, fp16 operands. WG = (b,vc,g), grid 768.
// Stage RAW qt (A) and RAW at in LDS once; per v: B frags = ds_read(at_l) *
// vtg8 via v_pk_mul_f16. Zero mid-loop barriers; marginal halves -> global
// partials; E_qa partials bf16 coalesced.
// ---------------------------------------------------------------------------
__global__ __launch_bounds__(256) void k_logits(
    const _Float16* __restrict__ vtg, const _Float16* __restrict__ qt,
    const _Float16* __restrict__ at,
    float* __restrict__ Evq_part, float* __restrict__ Eva_part,
    unsigned short* __restrict__ E_qa_part)
{
    int bid = blockIdx.x;
    int g = bid & 1, vc = (bid >> 1) % NCH, b = bid / (2 * NCH);
    int tid = threadIdx.x;

    __shared__ __align__(16) _Float16 qt_l[N_ * PAD];
    __shared__ __align__(16) _Float16 at_l[N_ * PAD];

    const _Float16* qtb = qt + (size_t)b * N_ * H_;
    const _Float16* atb = at + (size_t)b * N_ * H_;

    for (int it = 0; it < 12; it++) {
        int i = tid + it * 256;
        int e = i * 4, t = e >> 7, h = e & 127;
        *(ushort4*)&qt_l[t * PAD + h] = *(const ushort4*)&qtb[e];
        *(ushort4*)&at_l[t * PAD + h] = *(const ushort4*)&atb[e];
    }
    __syncthreads();   // the only barrier

    int wave = tid >> 6, lane = tid & 63, quad = lane >> 4, l15 = lane & 15;
    int qi0 = (wave >> 1) * 3, aj0 = (wave & 1) * 3;

    float eqa[3][3][4];
#pragma unroll
    for (int i = 0; i < 3; i++)
#pragma unroll
        for (int j = 0; j < 3; j++)
#pragma unroll
            for (int r = 0; r < 4; r++) eqa[i][j][r] = 0.f;

    for (int vl = 0; vl < CV; vl++) {
        int vrow = vc * CV + vl;
        const _Float16* vgp = vtg + ((size_t)(b * N_ + vrow) * 2 + g) * H_;

        f32x4_t acc[3][3];
#pragma unroll
        for (int i = 0; i < 3; i++)
#pragma unroll
            for (int j = 0; j < 3; j++)
                acc[i][j] = (f32x4_t){0.f, 0.f, 0.f, 0.f};

#pragma unroll
        for (int ks = 0; ks < 4; ks++) {
            f16x8 v8 = *(const f16x8*)&vgp[ks * 32 + quad * 8];
            f16x8 af[3], bfr[3];
#pragma unroll
            for (int i = 0; i < 3; i++)
                af[i] = *(const f16x8*)&qt_l[((qi0 + i) * 16 + l15) * PAD + ks * 32 + quad * 8];
#pragma unroll
            for (int jt = 0; jt < 3; jt++) {
                f16x8 raw = *(const f16x8*)&at_l[((aj0 + jt) * 16 + l15) * PAD + ks * 32 + quad * 8];
                bfr[jt] = raw * v8;                 // v_pk_mul_f16
            }
#pragma unroll
            for (int i = 0; i < 3; i++)
#pragma unroll
                for (int jt = 0; jt < 3; jt++)
                    acc[i][jt] = __builtin_amdgcn_mfma_f32_16x16x32_f16(af[i], bfr[jt], acc[i][jt], 0, 0, 0);
        }

        // C/D: col(a)=l15, row(q)=quad*4+r  [m89-verified, dtype-independent]
        float s[3][4];
        float c[3];
#pragma unroll
        for (int i = 0; i < 3; i++) {
            s[i][0] = 0.f; s[i][1] = 0.f; s[i][2] = 0.f; s[i][3] = 0.f;
        }
        c[0] = 0.f; c[1] = 0.f; c[2] = 0.f;
#pragma unroll
        for (int i = 0; i < 3; i++)
#pragma unroll
            for (int jt = 0; jt < 3; jt++) {
                float e0 = __expf(fminf(fmaxf(acc[i][jt][0], -30.f), 30.f));
                float e1 = __expf(fminf(fmaxf(acc[i][jt][1], -30.f), 30.f));
                float e2 = __expf(fminf(fmaxf(acc[i][jt][2], -30.f), 30.f));
                float e3 = __expf(fminf(fmaxf(acc[i][jt][3], -30.f), 30.f));
                eqa[i][jt][0] += e0; eqa[i][jt][1] += e1;
                eqa[i][jt][2] += e2; eqa[i][jt][3] += e3;
                s[i][0] += e0; s[i][1] += e1; s[i][2] += e2; s[i][3] += e3;
                c[jt] += e0 + e1 + e2 + e3;
            }

        float* evqp = Evq_part + ((size_t)bid * CV + vl) * 192 + (wave & 1) * 96;
#pragma unroll
        for (int i = 0; i < 3; i++) {
            float s0 = s[i][0], s1 = s[i][1], s2 = s[i][2], s3 = s[i][3];
#pragma unroll
            for (int m = 1; m < 16; m <<= 1) {
                s0 += __shfl_xor(s0, m); s1 += __shfl_xor(s1, m);
                s2 += __shfl_xor(s2, m); s3 += __shfl_xor(s3, m);
            }
            if (l15 == 0) {
                int qr = (qi0 + i) * 16 + quad * 4;
                evqp[qr + 0] = s0; evqp[qr + 1] = s1;
                evqp[qr + 2] = s2; evqp[qr + 3] = s3;
            }
        }
        float* evap = Eva_part + ((size_t)bid * CV + vl) * 192 + (wave >> 1) * 96;
#pragma unroll
        for (int jt = 0; jt < 3; jt++) {
            float cs = c[jt];
            cs += __shfl_xor(cs, 16);
            cs += __shfl_xor(cs, 32);
            if (lane < 16) evap[(aj0 + jt) * 16 + l15] = cs;
        }
    }

    unsigned short* Pp = E_qa_part + (size_t)bid * 9216;
#pragma unroll
    for (int i = 0; i < 3; i++)
#pragma unroll
        for (int jt = 0; jt < 3; jt++)
#pragma unroll
            for (int r = 0; r < 4; r++) {
                int idx = (i * 3 + jt) * 4 + r;
                union { float f; unsigned u; } x;
                x.f = eqa[i][jt][r];
                unsigned rr = x.u + 0x7fffu + ((x.u >> 16) & 1u);
                Pp[idx * 256 + tid] = (unsigned short)(rr >> 16);
            }
}

// ---------------------------------------------------------------------------
// Kernel 3 (R11): fused reduce+merge. grid = 1184.
// Blocks [0,1152): reduce bf16 E_qa partials over NCH vc slots.
// Blocks [1152,1184): merge E_vq/E_va halves + Zinv per (b,g).
// ---------------------------------------------------------------------------
__global__ __launch_bounds__(256) void k_mid(
    const unsigned short* __restrict__ E_qa_part,
    const float* __restrict__ Evq_part, const float* __restrict__ Eva_part,
    float* __restrict__ E_qa, float* __restrict__ E_vq,
    float* __restrict__ E_va, float* __restrict__ Zinv)
{
    int wg = blockIdx.x;
    int tid = threadIdx.x;
    if (wg < 1152) {
        int idx = wg % 36, bg = wg / 36;
        int b = bg >> 1, g = bg & 1;
        float s = 0.f;
        const unsigned short* Pp = E_qa_part + ((size_t)(b * 2 * NCH + g)) * 9216 + idx * 256 + tid;
#pragma unroll
        for (int vc = 0; vc < NCH; vc++) s += bf2f(Pp[(size_t)vc * 2 * 9216]);

        int wave = tid >> 6, lane = tid & 63, quad = lane >> 4, l15 = lane & 15;
        int qi0 = (wave >> 1) * 3, aj0 = (wave & 1) * 3;
        int i = idx / 12, jt = (idx / 4) % 3, r = idx & 3;
        int qq = (qi0 + i) * 16 + quad * 4 + r;
        int aa = (aj0 + jt) * 16 + l15;
        E_qa[(size_t)bg * 9216 + qq * 96 + aa] = s;
    } else {
        int bg = wg - 1152;
        int b = bg >> 1, g = bg & 1;
        float z = 0.f;
        for (int i = tid; i < 9216; i += 256) {
            int vrow = i / 96, col = i - vrow * 96;
            int vc = vrow / CV, vl = vrow - vc * CV;
            size_t pb = ((size_t)(b * 2 * NCH + vc * 2 + g) * CV + vl) * 192;
            float s1 = Evq_part[pb + col] + Evq_part[pb + 96 + col];
            E_vq[(b * 2 + g) * 9216 + i] = s1;
            z += s1;
            float s2 = Eva_part[pb + col] + Eva_part[pb + 96 + col];
            E_va[(b * 2 + g) * 9216 + i] = s2;
        }
        __shared__ float red[256];
        red[tid] = z;
        __syncthreads();
        for (int s = 128; s > 0; s >>= 1) {
            if (tid < s) red[tid] += red[tid + s];
            __syncthreads();
        }
        if (tid == 0) Zinv[b * 2 + g] = 1.f / fmaxf(red[0], 1e-30f);
    }
}

// ---------------------------------------------------------------------------
// Kernel 4 (R11): fused ctx+update. WG = (o, b, tc of 8 tokens), grid 576,
// both g per WG. Phase 1 (thread=(g,d)): c rows from marginals into LDS at
// final column position (c_v/c_q col=g*128+d, c_a col=d*2+g). Phase 2
// (thread=n): out = x + c @ Wxu + bxu, written once (no d_out scratch).
// ---------------------------------------------------------------------------
__global__ __launch_bounds__(256) void k_ctxup(
    const float* __restrict__ E_vq, const float* __restrict__ E_va,
    const float* __restrict__ E_qa,
    const float* __restrict__ vp, const float* __restrict__ qp,
    const float* __restrict__ ap, const float* __restrict__ Zinv,
    const float* __restrict__ v, const float* __restrict__ q,
    const float* __restrict__ a,
    const float* __restrict__ Wvu, const float* __restrict__ bvu,
    const float* __restrict__ Wqu, const float* __restrict__ bqu,
    const float* __restrict__ Wau, const float* __restrict__ bau,
    float* __restrict__ out)
{
    int wg = blockIdx.x;
    int tc = wg % 12, b = (wg / 12) & 15, o = wg / 192;
    int tid = threadIdx.x;
    int t0 = tc * 8;

    __shared__ __align__(16) float E1l[2][8 * 100];   // 6.4 KB
    __shared__ __align__(16) float E2l[2][8 * 100];   // 6.4 KB
    __shared__ __align__(16) float c_l[8 * 256];      // 8 KB

    for (int i = tid; i < 1536; i += 256) {
        int g2 = i / 768, rem = i - g2 * 768;
        int t = rem / 96, j = rem - t * 96;
        const float* Evq = E_vq + (b * 2 + g2) * 9216;
        const float* Eva = E_va + (b * 2 + g2) * 9216;
        const float* Eqa = E_qa + (b * 2 + g2) * 9216;
        float e1, e2;
        if (o == 0)      { e1 = Evq[(t0 + t) * 96 + j]; e2 = Eva[(t0 + t) * 96 + j]; }
        else if (o == 1) { e1 = Evq[j * 96 + t0 + t];   e2 = Eqa[(t0 + t) * 96 + j]; }
        else             { e1 = Eva[j * 96 + t0 + t];   e2 = Eqa[j * 96 + t0 + t]; }
        E1l[g2][t * 100 + j] = e1;
        E2l[g2][t * 100 + j] = e2;
    }
    __syncthreads();

    {   // ctx phase: thread = (g2, d)
        int d = tid & 127, g2 = tid >> 7;
        const float* P1 = ((o == 0) ? qp : vp) + b * N_ * H_;
        const float* P2 = ((o == 2) ? qp : ap) + b * N_ * H_;
        float acc[8] = {0.f, 0.f, 0.f, 0.f, 0.f, 0.f, 0.f, 0.f};
        for (int jb = 0; jb < 24; jb++) {
            int j4 = jb * 4;
            float p10 = P1[(j4 + 0) * H_ + d], p11 = P1[(j4 + 1) * H_ + d];
            float p12 = P1[(j4 + 2) * H_ + d], p13 = P1[(j4 + 3) * H_ + d];
            float p20 = P2[(j4 + 0) * H_ + d], p21 = P2[(j4 + 1) * H_ + d];
            float p22 = P2[(j4 + 2) * H_ + d], p23 = P2[(j4 + 3) * H_ + d];
#pragma unroll
            for (int t8 = 0; t8 < 8; t8++) {
                float4 e1 = *(const float4*)&E1l[g2][t8 * 100 + j4];
                float4 e2 = *(const float4*)&E2l[g2][t8 * 100 + j4];
                acc[t8] += e1.x * p10 + e1.y * p11 + e1.z * p12 + e1.w * p13
                         + e2.x * p20 + e2.y * p21 + e2.z * p22 + e2.w * p23;
            }
        }
        float zi = Zinv[b * 2 + g2];
        int col = (o == 2) ? (d * 2 + g2) : (g2 * 128 + d);
#pragma unroll
        for (int t8 = 0; t8 < 8; t8++)
            c_l[t8 * 256 + col] = acc[t8] * zi;
    }
    __syncthreads();

    // update phase: thread = output column n
    const float* xs_[3] = {v, q, a};
    const float* Ws_[3] = {Wvu, Wqu, Wau};
    const float* bs_[3] = {bvu, bqu, bau};
    const float* W = Ws_[o];
    const float* x = xs_[o] + (size_t)(b * N_ + t0) * 256;
    float bias = bs_[o][tid];
    float acc[8];
#pragma unroll
    for (int t = 0; t < 8; t++) acc[t] = bias + x[t * 256 + tid];

    for (int kb = 0; kb < 64; kb++) {
        int k = kb * 4;
        float w0 = W[(k + 0) * 256 + tid];
        float w1 = W[(k + 1) * 256 + tid];
        float w2 = W[(k + 2) * 256 + tid];
        float w3 = W[(k + 3) * 256 + tid];
#pragma unroll
        for (int t = 0; t < 8; t++) {
            float4 c4 = *(const float4*)&c_l[t * 256 + k];
            acc[t] += c4.x * w0 + c4.y * w1 + c4.z * w2 + c4.w * w3;
        }
    }
    float* ob = out + (size_t)((o * B_ + b) * N_ + t0) * 256;
#pragma unroll
    for (int t = 0; t < 8; t++) ob[t * 256 + tid] = acc[t];
}

// ---------------------------------------------------------------------------
extern "C" void kernel_launch(void* const* d_in, const int* in_sizes, int n_in,
                              void* d_out, int out_size, void* d_ws, size_t ws_size,
                              hipStream_t stream)
{
    const float* v   = (const float*)d_in[0];
    const float* q   = (const float*)d_in[1];
    const float* a   = (const float*)d_in[2];
    const float* Wvt = (const float*)d_in[3];
    const float* bvt = (const float*)d_in[4];
    const float* Wqt = (const float*)d_in[5];
    const float* bqt = (const float*)d_in[6];
    const float* Wat = (const float*)d_in[7];
    const float* bat = (const float*)d_in[8];
    const float* Wg  = (const float*)d_in[9];
    const float* Wvp = (const float*)d_in[10];
    const float* bvp = (const float*)d_in[11];
    const float* Wqp = (const float*)d_in[12];
    const float* bqp = (const float*)d_in[13];
    const float* Wap = (const float*)d_in[14];
    const float* bap = (const float*)d_in[15];
    const float* Wvu = (const float*)d_in[16];
    const float* bvu = (const float*)d_in[17];
    const float* Wqu = (const float*)d_in[18];
    const float* bqu = (const float*)d_in[19];
    const float* Wau = (const float*)d_in[20];
    const float* bau = (const float*)d_in[21];

    char* ws = (char*)d_ws;
    size_t off = 0;
    auto alloc = [&](size_t bytes) {
        char* p = ws + off;
        off += (bytes + 255) & ~(size_t)255;
        return (void*)p;
    };
    _Float16* vtg = (_Float16*)alloc((size_t)B_ * N_ * 2 * H_ * 2);   // 786 KB
    _Float16* qt  = (_Float16*)alloc((size_t)B_ * N_ * H_ * 2);
    _Float16* at  = (_Float16*)alloc((size_t)B_ * N_ * H_ * 2);
    float* vpb  = (float*)alloc((size_t)B_ * N_ * H_ * 4);
    float* qpb  = (float*)alloc((size_t)B_ * N_ * H_ * 4);
    float* apb  = (float*)alloc((size_t)B_ * N_ * H_ * 4);
    float* E_vq = (float*)alloc((size_t)B_ * 2 * 9216 * 4);
    float* E_va = (float*)alloc((size_t)B_ * 2 * 9216 * 4);
    float* E_qa = (float*)alloc((size_t)B_ * 2 * 9216 * 4);
    float* Zinv = (float*)alloc(256);
    float* Evq_part = (float*)alloc((size_t)768 * CV * 192 * 4);   // 2.36 MB
    float* Eva_part = (float*)alloc((size_t)768 * CV * 192 * 4);   // 2.36 MB
    unsigned short* E_qa_part =
        (unsigned short*)alloc((size_t)B_ * NCH * 2 * 9216 * 2);   // 14.2 MB bf16
    // total ~26 MB

    k_proj<<<768, 256, 0, stream>>>(v, q, a, Wvt, bvt, Wqt, bqt, Wat, bat,
                                    Wvp, bvp, Wqp, bqp, Wap, bap, Wg,
                                    vtg, qt, at, vpb, qpb, apb);
    k_logits<<<B_ * NCH * 2, 256, 0, stream>>>(vtg, qt, at,
                                               Evq_part, Eva_part, E_qa_part);
    k_mid<<<1184, 256, 0, stream>>>(E_qa_part, Evq_part, Eva_part,
                                    E_qa, E_vq, E_va, Zinv);
    k_ctxup<<<576, 256, 0, stream>>>(E_vq, E_va, E_qa, vpb, qpb, apb, Zinv,
                                     v, q, a, Wvu, bvu, Wqu, bqu, Wau, bau,
                                     (float*)d_out);
}

// Round 12
// 198.466 us; speedup vs baseline: 1.3808x; 1.0043x over previous
//
#include <hip/hip_runtime.h>

// TriAttention factorized implementation — all-f32 I/O, fp16 MFMA logits.
// dims: B=16, N(v,q,a)=96, D=256, H=128, G=2
// l[v,q,a,g] = sum_h qt[q,h] * (at[a,h]*vt[v,h]*Wg[h,g]); contractions
// factor through pairwise marginals of softmax(l) (p never materialized).
// R12: k_ctxup split to 4 tokens/WG, grid 1152 (was 576) — R11 profile
// showed it grid-starved (2.25 WG/CU, Occ 17.9%, BW 590 GB/s << ceiling).

#define B_  16
#define N_  96
#define D_  256
#define H_  128
#define CV  4     // v rows per k_logits workgroup
#define NCH 24    // v-chunks = 96/CV
#define PAD 136   // LDS row stride in f16 elems (272 B, 16B-aligned)

typedef _Float16 f16x8 __attribute__((ext_vector_type(8)));
typedef float f32x4_t  __attribute__((ext_vector_type(4)));

__device__ __forceinline__ float bf2f(unsigned short u) {
    union { unsigned u32; float f; } x;
    x.u32 = ((unsigned)u) << 16;
    return x.f;
}

// ---------------------------------------------------------------------------
// Kernel 1: six projections x@W+b -> [B,96,128].
// p=0: vtg[b,v,g,h] = relu(vt)*Wg[h,g] f16 (both g). p=1,2: relu'd f16.
// p>=3: value projections f32. grid = 768 (3 WG/CU), 12 tokens/WG.
// ---------------------------------------------------------------------------
__global__ __launch_bounds__(256) void k_proj(
    const float* __restrict__ v, const float* __restrict__ q,
    const float* __restrict__ a,
    const float* __restrict__ Wvt, const float* __restrict__ bvt,
    const float* __restrict__ Wqt, const float* __restrict__ bqt,
    const float* __restrict__ Wat, const float* __restrict__ bat,
    const float* __restrict__ Wvp, const float* __restrict__ bvp,
    const float* __restrict__ Wqp, const float* __restrict__ bqp,
    const float* __restrict__ Wap, const float* __restrict__ bap,
    const float* __restrict__ Wg,
    _Float16* __restrict__ vtg_o, _Float16* __restrict__ qt_o,
    _Float16* __restrict__ at_o,
    float* __restrict__ vp_o, float* __restrict__ qp_o, float* __restrict__ ap_o)
{
    int wg = blockIdx.x;
    int tc = wg % 8, b = (wg / 8) & 15, p = wg / 128;
    const float* xs_[6] = {v, q, a, v, q, a};
    const float* Ws_[6] = {Wvt, Wqt, Wat, Wvp, Wqp, Wap};
    const float* bs_[6] = {bvt, bqt, bat, bvp, bqp, bap};

    __shared__ __align__(16) float x_l[12 * D_];   // 12 KB

    int tid = threadIdx.x;
    int t0 = tc * 12;
    const float* x = xs_[p] + (size_t)(b * N_ + t0) * D_;
    for (int i = tid; i < 768; i += 256)
        ((float4*)x_l)[i] = ((const float4*)x)[i];
    __syncthreads();

    int d = tid & 127, tg = tid >> 7;
    const float* W = Ws_[p];
    float bias = bs_[p][d];
    float acc[6];
#pragma unroll
    for (int t = 0; t < 6; t++) acc[t] = bias;

    for (int kb = 0; kb < 32; kb++) {
        int k = kb * 8;
        float w0 = W[(k + 0) * H_ + d], w1 = W[(k + 1) * H_ + d];
        float w2 = W[(k + 2) * H_ + d], w3 = W[(k + 3) * H_ + d];
        float w4 = W[(k + 4) * H_ + d], w5 = W[(k + 5) * H_ + d];
        float w6 = W[(k + 6) * H_ + d], w7 = W[(k + 7) * H_ + d];
#pragma unroll
        for (int t = 0; t < 6; t++) {
            int lt = tg * 6 + t;
            float4 xa = *(const float4*)&x_l[lt * D_ + k];
            float4 xb = *(const float4*)&x_l[lt * D_ + k + 4];
            acc[t] += xa.x * w0 + xa.y * w1 + xa.z * w2 + xa.w * w3
                    + xb.x * w4 + xb.y * w5 + xb.z * w6 + xb.w * w7;
        }
    }

    int trow = b * N_ + t0 + tg * 6;
    if (p == 0) {
        float wg0 = Wg[d * 2 + 0], wg1 = Wg[d * 2 + 1];
#pragma unroll
        for (int t = 0; t < 6; t++) {
            float r = fmaxf(acc[t], 0.f);                     // FCNet relu
            _Float16* vg = vtg_o + (size_t)(trow + t) * 2 * H_;
            vg[d]      = (_Float16)(r * wg0);
            vg[H_ + d] = (_Float16)(r * wg1);
        }
    } else if (p < 3) {
        _Float16* o = (p == 1) ? qt_o : at_o;
#pragma unroll
        for (int t = 0; t < 6; t++)
            o[(trow + t) * H_ + d] = (_Float16)fmaxf(acc[t], 0.f);
    } else {
        float* outs[3] = {vp_o, qp_o, ap_o};
        float* o = outs[p - 3];
#pragma unroll
        for (int t = 0; t < 6; t++) o[(trow + t) * H_ + d] = acc[t];
    }
}

// ---------------------------------------------------------------------------
// Kernel 2: logits + exp + marginals, fp16 operands. WG = (b,vc,g), grid 768.
// Stage RAW qt (A) and RAW at in LDS once; per v: B frags = ds_read(at_l) *
// vtg8 via v_pk_mul_f16. Zero mid-loop barriers; marginal halves -> global
// partials; E_qa partials bf16 coalesced.
// ---------------------------------------------------------------------------
__global__ __launch_bounds__(256) void k_logits(
    const _Float16* __restrict__ vtg, const _Float16* __restrict__ qt,
    const _Float16* __restrict__ at,
    float* __restrict__ Evq_part, float* __restrict__ Eva_part,
    unsigned short* __restrict__ E_qa_part)
{
    int bid = blockIdx.x;
    int g = bid & 1, vc = (bid >> 1) % NCH, b = bid / (2 * NCH);
    int tid = threadIdx.x;

    __shared__ __align__(16) _Float16 qt_l[N_ * PAD];
    __shared__ __align__(16) _Float16 at_l[N_ * PAD];

    const _Float16* qtb = qt + (size_t)b * N_ * H_;
    const _Float16* atb = at + (size_t)b * N_ * H_;

    for (int it = 0; it < 12; it++) {
        int i = tid + it * 256;
        int e = i * 4, t = e >> 7, h = e & 127;
        *(ushort4*)&qt_l[t * PAD + h] = *(const ushort4*)&qtb[e];
        *(ushort4*)&at_l[t * PAD + h] = *(const ushort4*)&atb[e];
    }
    __syncthreads();   // the only barrier

    int wave = tid >> 6, lane = tid & 63, quad = lane >> 4, l15 = lane & 15;
    int qi0 = (wave >> 1) * 3, aj0 = (wave & 1) * 3;

    float eqa[3][3][4];
#pragma unroll
    for (int i = 0; i < 3; i++)
#pragma unroll
        for (int j = 0; j < 3; j++)
#pragma unroll
            for (int r = 0; r < 4; r++) eqa[i][j][r] = 0.f;

    for (int vl = 0; vl < CV; vl++) {
        int vrow = vc * CV + vl;
        const _Float16* vgp = vtg + ((size_t)(b * N_ + vrow) * 2 + g) * H_;

        f32x4_t acc[3][3];
#pragma unroll
        for (int i = 0; i < 3; i++)
#pragma unroll
            for (int j = 0; j < 3; j++)
                acc[i][j] = (f32x4_t){0.f, 0.f, 0.f, 0.f};

#pragma unroll
        for (int ks = 0; ks < 4; ks++) {
            f16x8 v8 = *(const f16x8*)&vgp[ks * 32 + quad * 8];
            f16x8 af[3], bfr[3];
#pragma unroll
            for (int i = 0; i < 3; i++)
                af[i] = *(const f16x8*)&qt_l[((qi0 + i) * 16 + l15) * PAD + ks * 32 + quad * 8];
#pragma unroll
            for (int jt = 0; jt < 3; jt++) {
                f16x8 raw = *(const f16x8*)&at_l[((aj0 + jt) * 16 + l15) * PAD + ks * 32 + quad * 8];
                bfr[jt] = raw * v8;                 // v_pk_mul_f16
            }
#pragma unroll
            for (int i = 0; i < 3; i++)
#pragma unroll
                for (int jt = 0; jt < 3; jt++)
                    acc[i][jt] = __builtin_amdgcn_mfma_f32_16x16x32_f16(af[i], bfr[jt], acc[i][jt], 0, 0, 0);
        }

        // C/D: col(a)=l15, row(q)=quad*4+r  [m89-verified, dtype-independent]
        float s[3][4];
        float c[3];
#pragma unroll
        for (int i = 0; i < 3; i++) {
            s[i][0] = 0.f; s[i][1] = 0.f; s[i][2] = 0.f; s[i][3] = 0.f;
        }
        c[0] = 0.f; c[1] = 0.f; c[2] = 0.f;
#pragma unroll
        for (int i = 0; i < 3; i++)
#pragma unroll
            for (int jt = 0; jt < 3; jt++) {
                float e0 = __expf(fminf(fmaxf(acc[i][jt][0], -30.f), 30.f));
                float e1 = __expf(fminf(fmaxf(acc[i][jt][1], -30.f), 30.f));
                float e2 = __expf(fminf(fmaxf(acc[i][jt][2], -30.f), 30.f));
                float e3 = __expf(fminf(fmaxf(acc[i][jt][3], -30.f), 30.f));
                eqa[i][jt][0] += e0; eqa[i][jt][1] += e1;
                eqa[i][jt][2] += e2; eqa[i][jt][3] += e3;
                s[i][0] += e0; s[i][1] += e1; s[i][2] += e2; s[i][3] += e3;
                c[jt] += e0 + e1 + e2 + e3;
            }

        float* evqp = Evq_part + ((size_t)bid * CV + vl) * 192 + (wave & 1) * 96;
#pragma unroll
        for (int i = 0; i < 3; i++) {
            float s0 = s[i][0], s1 = s[i][1], s2 = s[i][2], s3 = s[i][3];
#pragma unroll
            for (int m = 1; m < 16; m <<= 1) {
                s0 += __shfl_xor(s0, m); s1 += __shfl_xor(s1, m);
                s2 += __shfl_xor(s2, m); s3 += __shfl_xor(s3, m);
            }
            if (l15 == 0) {
                int qr = (qi0 + i) * 16 + quad * 4;
                evqp[qr + 0] = s0; evqp[qr + 1] = s1;
                evqp[qr + 2] = s2; evqp[qr + 3] = s3;
            }
        }
        float* evap = Eva_part + ((size_t)bid * CV + vl) * 192 + (wave >> 1) * 96;
#pragma unroll
        for (int jt = 0; jt < 3; jt++) {
            float cs = c[jt];
            cs += __shfl_xor(cs, 16);
            cs += __shfl_xor(cs, 32);
            if (lane < 16) evap[(aj0 + jt) * 16 + l15] = cs;
        }
    }

    unsigned short* Pp = E_qa_part + (size_t)bid * 9216;
#pragma unroll
    for (int i = 0; i < 3; i++)
#pragma unroll
        for (int jt = 0; jt < 3; jt++)
#pragma unroll
            for (int r = 0; r < 4; r++) {
                int idx = (i * 3 + jt) * 4 + r;
                union { float f; unsigned u; } x;
                x.f = eqa[i][jt][r];
                unsigned rr = x.u + 0x7fffu + ((x.u >> 16) & 1u);
                Pp[idx * 256 + tid] = (unsigned short)(rr >> 16);
            }
}

// ---------------------------------------------------------------------------
// Kernel 3: fused reduce+merge. grid = 1184.
// Blocks [0,1152): reduce bf16 E_qa partials over NCH vc slots.
// Blocks [1152,1184): merge E_vq/E_va halves + Zinv per (b,g).
// ---------------------------------------------------------------------------
__global__ __launch_bounds__(256) void k_mid(
    const unsigned short* __restrict__ E_qa_part,
    const float* __restrict__ Evq_part, const float* __restrict__ Eva_part,
    float* __restrict__ E_qa, float* __restrict__ E_vq,
    float* __restrict__ E_va, float* __restrict__ Zinv)
{
    int wg = blockIdx.x;
    int tid = threadIdx.x;
    if (wg < 1152) {
        int idx = wg % 36, bg = wg / 36;
        int b = bg >> 1, g = bg & 1;
        float s = 0.f;
        const unsigned short* Pp = E_qa_part + ((size_t)(b * 2 * NCH + g)) * 9216 + idx * 256 + tid;
#pragma unroll
        for (int vc = 0; vc < NCH; vc++) s += bf2f(Pp[(size_t)vc * 2 * 9216]);

        int wave = tid >> 6, lane = tid & 63, quad = lane >> 4, l15 = lane & 15;
        int qi0 = (wave >> 1) * 3, aj0 = (wave & 1) * 3;
        int i = idx / 12, jt = (idx / 4) % 3, r = idx & 3;
        int qq = (qi0 + i) * 16 + quad * 4 + r;
        int aa = (aj0 + jt) * 16 + l15;
        E_qa[(size_t)bg * 9216 + qq * 96 + aa] = s;
    } else {
        int bg = wg - 1152;
        int b = bg >> 1, g = bg & 1;
        float z = 0.f;
        for (int i = tid; i < 9216; i += 256) {
            int vrow = i / 96, col = i - vrow * 96;
            int vc = vrow / CV, vl = vrow - vc * CV;
            size_t pb = ((size_t)(b * 2 * NCH + vc * 2 + g) * CV + vl) * 192;
            float s1 = Evq_part[pb + col] + Evq_part[pb + 96 + col];
            E_vq[(b * 2 + g) * 9216 + i] = s1;
            z += s1;
            float s2 = Eva_part[pb + col] + Eva_part[pb + 96 + col];
            E_va[(b * 2 + g) * 9216 + i] = s2;
        }
        __shared__ float red[256];
        red[tid] = z;
        __syncthreads();
        for (int s = 128; s > 0; s >>= 1) {
            if (tid < s) red[tid] += red[tid + s];
            __syncthreads();
        }
        if (tid == 0) Zinv[b * 2 + g] = 1.f / fmaxf(red[0], 1e-30f);
    }
}

// ---------------------------------------------------------------------------
// Kernel 4 (R12): fused ctx+update, 4 tokens/WG. WG = (o, b, tc of 4),
// grid = 1152 (4.5 WG/CU), both g per WG. Phase 1 (thread=(g,d)): c rows
// from marginals into LDS at final column position. Phase 2 (thread=n):
// out = x + c @ Wxu + bxu, written once.
// ---------------------------------------------------------------------------
__global__ __launch_bounds__(256) void k_ctxup(
    const float* __restrict__ E_vq, const float* __restrict__ E_va,
    const float* __restrict__ E_qa,
    const float* __restrict__ vp, const float* __restrict__ qp,
    const float* __restrict__ ap, const float* __restrict__ Zinv,
    const float* __restrict__ v, const float* __restrict__ q,
    const float* __restrict__ a,
    const float* __restrict__ Wvu, const float* __restrict__ bvu,
    const float* __restrict__ Wqu, const float* __restrict__ bqu,
    const float* __restrict__ Wau, const float* __restrict__ bau,
    float* __restrict__ out)
{
    int wg = blockIdx.x;
    int tc = wg % 24, b = (wg / 24) & 15, o = wg / 384;
    int tid = threadIdx.x;
    int t0 = tc * 4;

    __shared__ __align__(16) float E1l[2][4 * 100];   // 3.2 KB
    __shared__ __align__(16) float E2l[2][4 * 100];   // 3.2 KB
    __shared__ __align__(16) float c_l[4 * 256];      // 4 KB

    for (int i = tid; i < 768; i += 256) {
        int g2 = i / 384, rem = i - g2 * 384;
        int t = rem / 96, j = rem - t * 96;
        const float* Evq = E_vq + (b * 2 + g2) * 9216;
        const float* Eva = E_va + (b * 2 + g2) * 9216;
        const float* Eqa = E_qa + (b * 2 + g2) * 9216;
        float e1, e2;
        if (o == 0)      { e1 = Evq[(t0 + t) * 96 + j]; e2 = Eva[(t0 + t) * 96 + j]; }
        else if (o == 1) { e1 = Evq[j * 96 + t0 + t];   e2 = Eqa[(t0 + t) * 96 + j]; }
        else             { e1 = Eva[j * 96 + t0 + t];   e2 = Eqa[j * 96 + t0 + t]; }
        E1l[g2][t * 100 + j] = e1;
        E2l[g2][t * 100 + j] = e2;
    }
    __syncthreads();

    {   // ctx phase: thread = (g2, d)
        int d = tid & 127, g2 = tid >> 7;
        const float* P1 = ((o == 0) ? qp : vp) + b * N_ * H_;
        const float* P2 = ((o == 2) ? qp : ap) + b * N_ * H_;
        float acc[4] = {0.f, 0.f, 0.f, 0.f};
        for (int jb = 0; jb < 24; jb++) {
            int j4 = jb * 4;
            float p10 = P1[(j4 + 0) * H_ + d], p11 = P1[(j4 + 1) * H_ + d];
            float p12 = P1[(j4 + 2) * H_ + d], p13 = P1[(j4 + 3) * H_ + d];
            float p20 = P2[(j4 + 0) * H_ + d], p21 = P2[(j4 + 1) * H_ + d];
            float p22 = P2[(j4 + 2) * H_ + d], p23 = P2[(j4 + 3) * H_ + d];
#pragma unroll
            for (int t8 = 0; t8 < 4; t8++) {
                float4 e1 = *(const float4*)&E1l[g2][t8 * 100 + j4];
                float4 e2 = *(const float4*)&E2l[g2][t8 * 100 + j4];
                acc[t8] += e1.x * p10 + e1.y * p11 + e1.z * p12 + e1.w * p13
                         + e2.x * p20 + e2.y * p21 + e2.z * p22 + e2.w * p23;
            }
        }
        float zi = Zinv[b * 2 + g2];
        int col = (o == 2) ? (d * 2 + g2) : (g2 * 128 + d);
#pragma unroll
        for (int t8 = 0; t8 < 4; t8++)
            c_l[t8 * 256 + col] = acc[t8] * zi;
    }
    __syncthreads();

    // update phase: thread = output column n
    const float* xs_[3] = {v, q, a};
    const float* Ws_[3] = {Wvu, Wqu, Wau};
    const float* bs_[3] = {bvu, bqu, bau};
    const float* W = Ws_[o];
    const float* x = xs_[o] + (size_t)(b * N_ + t0) * 256;
    float bias = bs_[o][tid];
    float acc[4];
#pragma unroll
    for (int t = 0; t < 4; t++) acc[t] = bias + x[t * 256 + tid];

    for (int kb = 0; kb < 64; kb++) {
        int k = kb * 4;
        float w0 = W[(k + 0) * 256 + tid];
        float w1 = W[(k + 1) * 256 + tid];
        float w2 = W[(k + 2) * 256 + tid];
        float w3 = W[(k + 3) * 256 + tid];
#pragma unroll
        for (int t = 0; t < 4; t++) {
            float4 c4 = *(const float4*)&c_l[t * 256 + k];
            acc[t] += c4.x * w0 + c4.y * w1 + c4.z * w2 + c4.w * w3;
        }
    }
    float* ob = out + (size_t)((o * B_ + b) * N_ + t0) * 256;
#pragma unroll
    for (int t = 0; t < 4; t++) ob[t * 256 + tid] = acc[t];
}

// ---------------------------------------------------------------------------
extern "C" void kernel_launch(void* const* d_in, const int* in_sizes, int n_in,
                              void* d_out, int out_size, void* d_ws, size_t ws_size,
                              hipStream_t stream)
{
    const float* v   = (const float*)d_in[0];
    const float* q   = (const float*)d_in[1];
    const float* a   = (const float*)d_in[2];
    const float* Wvt = (const float*)d_in[3];
    const float* bvt = (const float*)d_in[4];
    const float* Wqt = (const float*)d_in[5];
    const float* bqt = (const float*)d_in[6];
    const float* Wat = (const float*)d_in[7];
    const float* bat = (const float*)d_in[8];
    const float* Wg  = (const float*)d_in[9];
    const float* Wvp = (const float*)d_in[10];
    const float* bvp = (const float*)d_in[11];
    const float* Wqp = (const float*)d_in[12];
    const float* bqp = (const float*)d_in[13];
    const float* Wap = (const float*)d_in[14];
    const float* bap = (const float*)d_in[15];
    const float* Wvu = (const float*)d_in[16];
    const float* bvu = (const float*)d_in[17];
    const float* Wqu = (const float*)d_in[18];
    const float* bqu = (const float*)d_in[19];
    const float* Wau = (const float*)d_in[20];
    const float* bau = (const float*)d_in[21];

    char* ws = (char*)d_ws;
    size_t off = 0;
    auto alloc = [&](size_t bytes) {
        char* p = ws + off;
        off += (bytes + 255) & ~(size_t)255;
        return (void*)p;
    };
    _Float16* vtg = (_Float16*)alloc((size_t)B_ * N_ * 2 * H_ * 2);   // 786 KB
    _Float16* qt  = (_Float16*)alloc((size_t)B_ * N_ * H_ * 2);
    _Float16* at  = (_Float16*)alloc((size_t)B_ * N_ * H_ * 2);
    float* vpb  = (float*)alloc((size_t)B_ * N_ * H_ * 4);
    float* qpb  = (float*)alloc((size_t)B_ * N_ * H_ * 4);
    float* apb  = (float*)alloc((size_t)B_ * N_ * H_ * 4);
    float* E_vq = (float*)alloc((size_t)B_ * 2 * 9216 * 4);
    float* E_va = (float*)alloc((size_t)B_ * 2 * 9216 * 4);
    float* E_qa = (float*)alloc((size_t)B_ * 2 * 9216 * 4);
    float* Zinv = (float*)alloc(256);
    float* Evq_part = (float*)alloc((size_t)768 * CV * 192 * 4);   // 2.36 MB
    float* Eva_part = (float*)alloc((size_t)768 * CV * 192 * 4);   // 2.36 MB
    unsigned short* E_qa_part =
        (unsigned short*)alloc((size_t)B_ * NCH * 2 * 9216 * 2);   // 14.2 MB bf16
    // total ~26 MB

    k_proj<<<768, 256, 0, stream>>>(v, q, a, Wvt, bvt, Wqt, bqt, Wat, bat,
                                    Wvp, bvp, Wqp, bqp, Wap, bap, Wg,
                                    vtg, qt, at, vpb, qpb, apb);
    k_logits<<<B_ * NCH * 2, 256, 0, stream>>>(vtg, qt, at,
                                               Evq_part, Eva_part, E_qa_part);
    k_mid<<<1184, 256, 0, stream>>>(E_qa_part, Evq_part, Eva_part,
                                    E_qa, E_vq, E_va, Zinv);
    k_ctxup<<<1152, 256, 0, stream>>>(E_vq, E_va, E_qa, vpb, qpb, apb, Zinv,
                                      v, q, a, Wvu, bvu, Wqu, bqu, Wau, bau,
                                      (float*)d_out);
}